// Round 4
// baseline (521.295 us; speedup 1.0000x reference)
//
#include <hip/hip_runtime.h>
#include <cstdint>
#include <cstddef>

#define LA 4096
#define LB 4096
#define DD 1024

typedef unsigned short u16;
typedef short bf16x8 __attribute__((ext_vector_type(8)));
typedef float f32x4 __attribute__((ext_vector_type(4)));

__device__ __forceinline__ u16 f2bf(float f) {
  unsigned u = __builtin_bit_cast(unsigned, f);
  u += 0x7fffu + ((u >> 16) & 1u);
  return (u16)(u >> 16);
}
__device__ __forceinline__ float bf2f(u16 h) {
  return __builtin_bit_cast(float, (unsigned)h << 16);
}
// async global->LDS, 16B/lane; lds base must be wave-uniform (HW adds lane*16)
__device__ __forceinline__ void async16(const void* g, void* l) {
  __builtin_amdgcn_global_load_lds(
      (const __attribute__((address_space(1))) unsigned int*)g,
      (__attribute__((address_space(3))) unsigned int*)l, 16, 0, 0);
}

// ---- prepass: split fp32 X -> Xhi + Xlo (bf16 residual pair) ---------------
__global__ __launch_bounds__(256) void split_ab(const float* __restrict__ A,
                                                const float* __restrict__ B,
                                                u16* __restrict__ Ahi, u16* __restrict__ Alo,
                                                u16* __restrict__ Bhi, u16* __restrict__ Blo) {
  const int side = blockIdx.x >> 11;
  const size_t idx = ((size_t)(blockIdx.x & 2047) * 256 + threadIdx.x) * 8;
  const float* src = side ? B : A;
  u16* dh = side ? Bhi : Ahi;
  u16* dl = side ? Blo : Alo;
  const float4 a = *(const float4*)&src[idx];
  const float4 b = *(const float4*)&src[idx + 4];
  float v[8] = {a.x, a.y, a.z, a.w, b.x, b.y, b.z, b.w};
  bf16x8 hi, lo;
#pragma unroll
  for (int i = 0; i < 8; ++i) {
    const u16 h = f2bf(v[i]);
    hi[i] = (short)h;
    lo[i] = (short)f2bf(v[i] - bf2f(h));
  }
  *(bf16x8*)&dh[idx] = hi;
  *(bf16x8*)&dl[idx] = lo;
}

// ------- tiled transpose fp32 -> bf16: out[c][r] = bf16(in[r][c]) -----------
__global__ __launch_bounds__(256) void tr_f32(const float* __restrict__ in,
                                              u16* __restrict__ out,
                                              int R, int C) {
  __shared__ u16 t[32][33];
  const int c0 = blockIdx.x * 32, r0 = blockIdx.y * 32;
  const int tid = threadIdx.x;
  const int lr = tid >> 3, lc = (tid & 7) * 4;
  const float4 v = *(const float4*)&in[(size_t)(r0 + lr) * C + c0 + lc];
  t[lr][lc + 0] = f2bf(v.x); t[lr][lc + 1] = f2bf(v.y);
  t[lr][lc + 2] = f2bf(v.z); t[lr][lc + 3] = f2bf(v.w);
  __syncthreads();
  ushort4 w;
  w.x = t[lc + 0][lr]; w.y = t[lc + 1][lr]; w.z = t[lc + 2][lr]; w.w = t[lc + 3][lr];
  *(ushort4*)&out[(size_t)(c0 + lr) * R + r0 + lc] = w;
}

// ------- energy = A @ B^T, split-bf16 3-term, ASYNC staging (m97-style) -----
__global__ __launch_bounds__(256) void gemm_energy(const u16* __restrict__ Ahi,
                                                   const u16* __restrict__ Alo,
                                                   const u16* __restrict__ Bhi,
                                                   const u16* __restrict__ Blo,
                                                   float* __restrict__ E) {
  __shared__ u16 lah[128 * 32], lal[128 * 32], lbh[128 * 32], lbl[128 * 32];
  const int j0 = blockIdx.x * 128;
  const int i0 = blockIdx.y * 128;
  const int tid = threadIdx.x;
  const int lane = tid & 63, quad = lane >> 4, lq = lane & 15;
  const int wave = tid >> 6;
  const int wm = (wave & 1) * 64, wn = (wave >> 1) * 64;
  f32x4 acc[4][4] = {};
  for (int kt = 0; kt < DD; kt += 32) {
    if (kt) __syncthreads();
#pragma unroll
    for (int r = 0; r < 2; ++r) {
      const int chunk = wave * 128 + r * 64 + lane;
      const int row = chunk >> 2;
      const int kc = (chunk & 3) * 8;
      const int lofs = (wave * 128 + r * 64) * 16;
      const size_t ga = (size_t)(i0 + row) * DD + kt + kc;
      const size_t gb = (size_t)(j0 + row) * DD + kt + kc;
      async16(Ahi + ga, (char*)lah + lofs);
      async16(Alo + ga, (char*)lal + lofs);
      async16(Bhi + gb, (char*)lbh + lofs);
      async16(Blo + gb, (char*)lbl + lofs);
    }
    __syncthreads();
    bf16x8 fah[4], fal[4], fbh[4], fbl[4];
#pragma unroll
    for (int f = 0; f < 4; ++f) {
      fah[f] = *(const bf16x8*)&lah[(wm + f * 16 + lq) * 32 + quad * 8];
      fal[f] = *(const bf16x8*)&lal[(wm + f * 16 + lq) * 32 + quad * 8];
      fbh[f] = *(const bf16x8*)&lbh[(wn + f * 16 + lq) * 32 + quad * 8];
      fbl[f] = *(const bf16x8*)&lbl[(wn + f * 16 + lq) * 32 + quad * 8];
    }
#pragma unroll
    for (int fm = 0; fm < 4; ++fm)
#pragma unroll
      for (int fn = 0; fn < 4; ++fn) {
        acc[fm][fn] = __builtin_amdgcn_mfma_f32_16x16x32_bf16(fal[fm], fbh[fn], acc[fm][fn], 0, 0, 0);
        acc[fm][fn] = __builtin_amdgcn_mfma_f32_16x16x32_bf16(fah[fm], fbl[fn], acc[fm][fn], 0, 0, 0);
        acc[fm][fn] = __builtin_amdgcn_mfma_f32_16x16x32_bf16(fah[fm], fbh[fn], acc[fm][fn], 0, 0, 0);
      }
  }
#pragma unroll
  for (int fm = 0; fm < 4; ++fm)
#pragma unroll
    for (int fn = 0; fn < 4; ++fn)
#pragma unroll
      for (int r = 0; r < 4; ++r) {
        const int gi = i0 + wm + fm * 16 + quad * 4 + r;
        const int gj = j0 + wn + fn * 16 + lq;
        E[(size_t)gi * LB + gj] = acc[fm][fn][r];
      }
}

// ---- fused: row softmax stats + Pa[i][j]=bf16(exp(E-rmax)) + zero wave_a ---
__global__ __launch_bounds__(256) void row_softmax_pa(const float* __restrict__ E,
                                                      float* __restrict__ rinv,
                                                      u16* __restrict__ P,
                                                      float* __restrict__ wa) {
  __shared__ float red[8];
  const int row = blockIdx.x, tid = threadIdx.x;
  const float* e = E + (size_t)row * LB;
  float4 v[4];
#pragma unroll
  for (int c = 0; c < 4; ++c) v[c] = *(const float4*)&e[(c * 256 + tid) * 4];
  float m = -__builtin_inff();
#pragma unroll
  for (int c = 0; c < 4; ++c)
    m = fmaxf(m, fmaxf(fmaxf(v[c].x, v[c].y), fmaxf(v[c].z, v[c].w)));
#pragma unroll
  for (int o = 32; o > 0; o >>= 1) m = fmaxf(m, __shfl_down(m, o));
  if ((tid & 63) == 0) red[tid >> 6] = m;
  __syncthreads();
  m = fmaxf(fmaxf(red[0], red[1]), fmaxf(red[2], red[3]));
  float s = 0.f;
#pragma unroll
  for (int c = 0; c < 4; ++c)
    s += __expf(v[c].x - m) + __expf(v[c].y - m) + __expf(v[c].z - m) + __expf(v[c].w - m);
#pragma unroll
  for (int o = 32; o > 0; o >>= 1) s += __shfl_down(s, o);
  if ((tid & 63) == 0) red[4 + (tid >> 6)] = s;
  __syncthreads();
  if (tid == 0) rinv[row] = 1.f / (red[4] + red[5] + red[6] + red[7]);
#pragma unroll
  for (int c = 0; c < 4; ++c) {
    ushort4 w;
    w.x = f2bf(__expf(v[c].x - m));
    w.y = f2bf(__expf(v[c].y - m));
    w.z = f2bf(__expf(v[c].z - m));
    w.w = f2bf(__expf(v[c].w - m));
    *(ushort4*)&P[(size_t)row * LB + (c * 256 + tid) * 4] = w;
  }
  float4 z = {0.f, 0.f, 0.f, 0.f};
  *(float4*)&wa[(size_t)row * DD + tid * 4] = z;
}

// ---------------- column softmax stats --------------------------------------
__global__ __launch_bounds__(256) void col_partial(const float* __restrict__ E,
                                                   float* __restrict__ pmax,
                                                   float* __restrict__ psum) {
  const int c = blockIdx.x * 256 + threadIdx.x;
  const int rg = blockIdx.y;
  const float* e = E + (size_t)rg * 128 * LB + c;
  float m = -__builtin_inff(), s = 0.f;
#pragma unroll 4
  for (int r = 0; r < 128; ++r) {
    const float x = e[(size_t)r * LB];
    const float nm = fmaxf(m, x);
    s = s * __expf(m - nm) + __expf(x - nm);
    m = nm;
  }
  pmax[rg * LB + c] = m;
  psum[rg * LB + c] = s;
}

__global__ __launch_bounds__(256) void col_combine(const float* __restrict__ pmax,
                                                   const float* __restrict__ psum,
                                                   float* __restrict__ cmax,
                                                   float* __restrict__ cinv) {
  const int c = blockIdx.x * 256 + threadIdx.x;
  float m = -__builtin_inff(), s = 0.f;
#pragma unroll 4
  for (int g = 0; g < 32; ++g) {
    const float pm = pmax[g * LB + c], ps = psum[g * LB + c];
    const float nm = fmaxf(m, pm);
    s = s * __expf(m - nm) + ps * __expf(pm - nm);
    m = nm;
  }
  cmax[c] = m;
  cinv[c] = 1.f / s;
}

// ---- Pb[j][i] = bf16(exp(E[i][j] - cmax[j])), transposing ------------------
__global__ __launch_bounds__(256) void make_pb(const float* __restrict__ E,
                                               const float* __restrict__ cmax,
                                               u16* __restrict__ P) {
  __shared__ u16 t[32][33];
  const int j0 = blockIdx.x * 32;
  const int i0 = blockIdx.y * 32;
  const int tid = threadIdx.x;
  const int lr = tid >> 3, lc = (tid & 7) * 4;
  const float4 v = *(const float4*)&E[(size_t)(i0 + lr) * LB + j0 + lc];
  const float4 cm = *(const float4*)&cmax[j0 + lc];
  t[lr][lc + 0] = f2bf(__expf(v.x - cm.x));
  t[lr][lc + 1] = f2bf(__expf(v.y - cm.y));
  t[lr][lc + 2] = f2bf(__expf(v.z - cm.z));
  t[lr][lc + 3] = f2bf(__expf(v.w - cm.w));
  __syncthreads();
  ushort4 w;
  w.x = t[lc + 0][lr]; w.y = t[lc + 1][lr]; w.z = t[lc + 2][lr]; w.w = t[lc + 3][lr];
  *(ushort4*)&P[(size_t)(j0 + lr) * LA + i0 + lc] = w;
}

// ---- W[i][d] += inv[i] * sum_j P[i][j] Vt[d][j], split-K x4 atomic ---------
// Grid (DD/128, L/128, 4) = 1024 blocks -> 4 blocks/CU (VGPR-cap 16 waves/CU),
// restoring the wave-level MFMA/staging overlap the m97 structure needs.
__global__ __launch_bounds__(256) void gemm_pv(const u16* __restrict__ P,
                                               const u16* __restrict__ Vt,
                                               const float* __restrict__ inv,
                                               float* __restrict__ W) {
  __shared__ u16 lds_a[128 * 32];
  __shared__ u16 lds_b[128 * 32];
  const int n0 = blockIdx.x * 128;
  const int i0 = blockIdx.y * 128;
  const int kt0 = blockIdx.z * 1024;
  const int tid = threadIdx.x;
  const int lane = tid & 63, quad = lane >> 4, lq = lane & 15;
  const int wave = tid >> 6;
  const int wm = (wave & 1) * 64, wn = (wave >> 1) * 64;
  f32x4 acc[4][4] = {};
  for (int t = 0; t < 32; ++t) {
    const int kt = kt0 + t * 32;
    if (t) __syncthreads();
#pragma unroll
    for (int r = 0; r < 2; ++r) {
      const int chunk = wave * 128 + r * 64 + lane;
      const int row = chunk >> 2;
      const int kc = (chunk & 3) * 8;
      const int lofs = (wave * 128 + r * 64) * 16;
      async16(P + (size_t)(i0 + row) * 4096 + kt + kc, (char*)lds_a + lofs);
      async16(Vt + (size_t)(n0 + row) * 4096 + kt + kc, (char*)lds_b + lofs);
    }
    __syncthreads();
    bf16x8 af[4], bfr[4];
#pragma unroll
    for (int f = 0; f < 4; ++f) {
      af[f]  = *(const bf16x8*)&lds_a[(wm + f * 16 + lq) * 32 + quad * 8];
      bfr[f] = *(const bf16x8*)&lds_b[(wn + f * 16 + lq) * 32 + quad * 8];
    }
#pragma unroll
    for (int fm = 0; fm < 4; ++fm)
#pragma unroll
      for (int fn = 0; fn < 4; ++fn)
        acc[fm][fn] = __builtin_amdgcn_mfma_f32_16x16x32_bf16(af[fm], bfr[fn], acc[fm][fn], 0, 0, 0);
  }
#pragma unroll
  for (int fm = 0; fm < 4; ++fm)
#pragma unroll
    for (int r = 0; r < 4; ++r) {
      const int gm = i0 + wm + fm * 16 + quad * 4 + r;
      const float sc = inv[gm];
#pragma unroll
      for (int fn = 0; fn < 4; ++fn) {
        const int gn = n0 + wn + fn * 16 + lq;
        unsafeAtomicAdd(&W[(size_t)gm * DD + gn], acc[fm][fn][r] * sc);
      }
    }
}

// ---------------- zero helper for atomic split-K ----------------------------
__global__ __launch_bounds__(256) void wb_zero(float* __restrict__ w) {
  const size_t idx = ((size_t)blockIdx.x * 256 + threadIdx.x) * 8;
  const float4 z = {0.f, 0.f, 0.f, 0.f};
  *(float4*)&w[idx] = z;
  *(float4*)&w[idx + 4] = z;
}

// ---------------- elementwise finish (FP32 out): copy / a-w / a*w -----------
__global__ __launch_bounds__(256) void finish(const float* __restrict__ Ain,
                                              const float* __restrict__ Bin,
                                              float* __restrict__ out) {
  const int side = blockIdx.x >> 11;
  const int blk = blockIdx.x & 2047;
  const size_t idx = ((size_t)blk * 256 + threadIdx.x) * 8;
  const size_t S = (size_t)LA * DD;
  const float* src = side ? Bin : Ain;
  float* ob = out + (size_t)side * 4 * S;
  const float4 a0 = *(const float4*)&src[idx];
  const float4 a1 = *(const float4*)&src[idx + 4];
  const float4 w0 = *(const float4*)&ob[S + idx];
  const float4 w1 = *(const float4*)&ob[S + idx + 4];
  float4 s0, s1, m0, m1;
  s0.x = a0.x - w0.x; s0.y = a0.y - w0.y; s0.z = a0.z - w0.z; s0.w = a0.w - w0.w;
  s1.x = a1.x - w1.x; s1.y = a1.y - w1.y; s1.z = a1.z - w1.z; s1.w = a1.w - w1.w;
  m0.x = a0.x * w0.x; m0.y = a0.y * w0.y; m0.z = a0.z * w0.z; m0.w = a0.w * w0.w;
  m1.x = a1.x * w1.x; m1.y = a1.y * w1.y; m1.z = a1.z * w1.z; m1.w = a1.w * w1.w;
  *(float4*)&ob[idx] = a0;            *(float4*)&ob[idx + 4] = a1;
  *(float4*)&ob[2 * S + idx] = s0;    *(float4*)&ob[2 * S + idx + 4] = s1;
  *(float4*)&ob[3 * S + idx] = m0;    *(float4*)&ob[3 * S + idx + 4] = m1;
}

extern "C" void kernel_launch(void* const* d_in, const int* in_sizes, int n_in,
                              void* d_out, int out_size, void* d_ws, size_t ws_size,
                              hipStream_t stream) {
  const float* A = (const float*)d_in[0];
  const float* B = (const float*)d_in[1];
  float* out = (float*)d_out;          // FP32 output: 8 slots of S floats
  const size_t S = (size_t)LA * DD;    // 4,194,304

  // d_ws UNUSED. Scratch choreography inside the 128 MiB fp32 out buffer:
  //   slot0: stats (1.1MB) + Bt (u16 at float-ofs 1M); finish side0 copy LAST
  //   slot1: wave_a (zeroed by row_softmax_pa, atomically accumulated)
  //   slots2-3: Ahi/Alo/Bhi/Blo (4x8MB) -> then Pa, then Pb (32MB)
  //   slots4-7: E (64MB) -> then At (slot4), wave_b (slot5), finish side1
  float* pmax = out;                       // 131072
  float* psum = pmax + 131072;             // 131072
  float* rmax = psum + 131072;             // unused, layout keeper
  float* rinv = rmax + 4096;
  float* cmax = rinv + 4096;
  float* cinv = cmax + 4096;
  u16*   Bt   = (u16*)(out + 1048576);     // [DD][LB] u16, 8MB
  u16*   Ahi  = (u16*)(out + 2 * S);       // 8MB each
  u16*   Alo  = Ahi + S;
  u16*   Bhi  = Alo + S;
  u16*   Blo  = Bhi + S;
  u16*   P    = (u16*)(out + 2 * S);       // [4096][4096] u16 (after hi/lo dead)
  float* E    = out + 4 * S;               // [4096][4096] fp32, 64MB
  u16*   At   = (u16*)(out + 4 * S);       // [DD][LA] u16 (after E consumed)
  float* wave_a = out + S;
  float* wave_b = out + 5 * S;

  split_ab<<<dim3(4096), 256, 0, stream>>>(A, B, Ahi, Alo, Bhi, Blo);
  gemm_energy<<<dim3(LB / 128, LA / 128), 256, 0, stream>>>(Ahi, Alo, Bhi, Blo, E);

  // row softmax + Pa in ONE E pass; also zeroes wave_a for the atomic PV
  row_softmax_pa<<<dim3(LA), 256, 0, stream>>>(E, rinv, P, wave_a);
  col_partial<<<dim3(LB / 256, 32), 256, 0, stream>>>(E, pmax, psum);
  col_combine<<<dim3(LB / 256), 256, 0, stream>>>(pmax, psum, cmax, cinv);

  // wave_a: split-K x4 atomic (1024 blocks -> 4 blocks/CU)
  tr_f32<<<dim3(DD / 32, LB / 32), 256, 0, stream>>>(B, Bt, LB, DD);
  gemm_pv<<<dim3(DD / 128, LA / 128, 4), 256, 0, stream>>>(P, Bt, rinv, wave_a);

  // wave_b: split-K x4 atomic into zeroed slot5
  make_pb<<<dim3(LB / 32, LA / 32), 256, 0, stream>>>(E, cmax, P);
  tr_f32<<<dim3(DD / 32, LA / 32), 256, 0, stream>>>(A, At, LA, DD);
  wb_zero<<<dim3(2048), 256, 0, stream>>>(wave_b);
  gemm_pv<<<dim3(DD / 128, LB / 128, 4), 256, 0, stream>>>(P, At, cinv, wave_b);

  finish<<<dim3(4096), 256, 0, stream>>>(A, B, out);
}

// Round 5
// 517.612 us; speedup vs baseline: 1.0071x; 1.0071x over previous
//
#include <hip/hip_runtime.h>
#include <cstdint>
#include <cstddef>

#define LA 4096
#define LB 4096
#define DD 1024

typedef unsigned short u16;
typedef short bf16x8 __attribute__((ext_vector_type(8)));
typedef float f32x4 __attribute__((ext_vector_type(4)));

__device__ __forceinline__ u16 f2bf(float f) {
  unsigned u = __builtin_bit_cast(unsigned, f);
  u += 0x7fffu + ((u >> 16) & 1u);
  return (u16)(u >> 16);
}
__device__ __forceinline__ float bf2f(u16 h) {
  return __builtin_bit_cast(float, (unsigned)h << 16);
}
// async global->LDS, 16B/lane; lds base must be wave-uniform (HW adds lane*16)
__device__ __forceinline__ void async16(const void* g, void* l) {
  __builtin_amdgcn_global_load_lds(
      (const __attribute__((address_space(1))) unsigned int*)g,
      (__attribute__((address_space(3))) unsigned int*)l, 16, 0, 0);
}

// ---- prepass: split fp32 X -> Xhi + Xlo (bf16 residual pair) ---------------
__global__ __launch_bounds__(256) void split_ab(const float* __restrict__ A,
                                                const float* __restrict__ B,
                                                u16* __restrict__ Ahi, u16* __restrict__ Alo,
                                                u16* __restrict__ Bhi, u16* __restrict__ Blo) {
  const int side = blockIdx.x >> 11;
  const size_t idx = ((size_t)(blockIdx.x & 2047) * 256 + threadIdx.x) * 8;
  const float* src = side ? B : A;
  u16* dh = side ? Bhi : Ahi;
  u16* dl = side ? Blo : Alo;
  const float4 a = *(const float4*)&src[idx];
  const float4 b = *(const float4*)&src[idx + 4];
  float v[8] = {a.x, a.y, a.z, a.w, b.x, b.y, b.z, b.w};
  bf16x8 hi, lo;
#pragma unroll
  for (int i = 0; i < 8; ++i) {
    const u16 h = f2bf(v[i]);
    hi[i] = (short)h;
    lo[i] = (short)f2bf(v[i] - bf2f(h));
  }
  *(bf16x8*)&dh[idx] = hi;
  *(bf16x8*)&dl[idx] = lo;
}

// ------- tiled transpose fp32 -> bf16: out[c][r] = bf16(in[r][c]) -----------
__global__ __launch_bounds__(256) void tr_f32(const float* __restrict__ in,
                                              u16* __restrict__ out,
                                              int R, int C) {
  __shared__ u16 t[32][33];
  const int c0 = blockIdx.x * 32, r0 = blockIdx.y * 32;
  const int tid = threadIdx.x;
  const int lr = tid >> 3, lc = (tid & 7) * 4;
  const float4 v = *(const float4*)&in[(size_t)(r0 + lr) * C + c0 + lc];
  t[lr][lc + 0] = f2bf(v.x); t[lr][lc + 1] = f2bf(v.y);
  t[lr][lc + 2] = f2bf(v.z); t[lr][lc + 3] = f2bf(v.w);
  __syncthreads();
  ushort4 w;
  w.x = t[lc + 0][lr]; w.y = t[lc + 1][lr]; w.z = t[lc + 2][lr]; w.w = t[lc + 3][lr];
  *(ushort4*)&out[(size_t)(c0 + lr) * R + r0 + lc] = w;
}

// ------- energy = A @ B^T, split-bf16 3-term, ASYNC staging (m97-style) -----
__global__ __launch_bounds__(256) void gemm_energy(const u16* __restrict__ Ahi,
                                                   const u16* __restrict__ Alo,
                                                   const u16* __restrict__ Bhi,
                                                   const u16* __restrict__ Blo,
                                                   float* __restrict__ E) {
  __shared__ u16 lah[128 * 32], lal[128 * 32], lbh[128 * 32], lbl[128 * 32];
  const int j0 = blockIdx.x * 128;
  const int i0 = blockIdx.y * 128;
  const int tid = threadIdx.x;
  const int lane = tid & 63, quad = lane >> 4, lq = lane & 15;
  const int wave = tid >> 6;
  const int wm = (wave & 1) * 64, wn = (wave >> 1) * 64;
  f32x4 acc[4][4] = {};
  for (int kt = 0; kt < DD; kt += 32) {
    if (kt) __syncthreads();
#pragma unroll
    for (int r = 0; r < 2; ++r) {
      const int chunk = wave * 128 + r * 64 + lane;
      const int row = chunk >> 2;
      const int kc = (chunk & 3) * 8;
      const int lofs = (wave * 128 + r * 64) * 16;
      const size_t ga = (size_t)(i0 + row) * DD + kt + kc;
      const size_t gb = (size_t)(j0 + row) * DD + kt + kc;
      async16(Ahi + ga, (char*)lah + lofs);
      async16(Alo + ga, (char*)lal + lofs);
      async16(Bhi + gb, (char*)lbh + lofs);
      async16(Blo + gb, (char*)lbl + lofs);
    }
    __syncthreads();
    bf16x8 fah[4], fal[4], fbh[4], fbl[4];
#pragma unroll
    for (int f = 0; f < 4; ++f) {
      fah[f] = *(const bf16x8*)&lah[(wm + f * 16 + lq) * 32 + quad * 8];
      fal[f] = *(const bf16x8*)&lal[(wm + f * 16 + lq) * 32 + quad * 8];
      fbh[f] = *(const bf16x8*)&lbh[(wn + f * 16 + lq) * 32 + quad * 8];
      fbl[f] = *(const bf16x8*)&lbl[(wn + f * 16 + lq) * 32 + quad * 8];
    }
#pragma unroll
    for (int fm = 0; fm < 4; ++fm)
#pragma unroll
      for (int fn = 0; fn < 4; ++fn) {
        acc[fm][fn] = __builtin_amdgcn_mfma_f32_16x16x32_bf16(fal[fm], fbh[fn], acc[fm][fn], 0, 0, 0);
        acc[fm][fn] = __builtin_amdgcn_mfma_f32_16x16x32_bf16(fah[fm], fbl[fn], acc[fm][fn], 0, 0, 0);
        acc[fm][fn] = __builtin_amdgcn_mfma_f32_16x16x32_bf16(fah[fm], fbh[fn], acc[fm][fn], 0, 0, 0);
      }
  }
#pragma unroll
  for (int fm = 0; fm < 4; ++fm)
#pragma unroll
    for (int fn = 0; fn < 4; ++fn)
#pragma unroll
      for (int r = 0; r < 4; ++r) {
        const int gi = i0 + wm + fm * 16 + quad * 4 + r;
        const int gj = j0 + wn + fn * 16 + lq;
        E[(size_t)gi * LB + gj] = acc[fm][fn][r];
      }
}

// ---- fused: row softmax stats + Pa[i][j]=bf16(exp(E-rmax)) + zero wave_a ---
__global__ __launch_bounds__(256) void row_softmax_pa(const float* __restrict__ E,
                                                      float* __restrict__ rinv,
                                                      u16* __restrict__ P,
                                                      float* __restrict__ wa) {
  __shared__ float red[8];
  const int row = blockIdx.x, tid = threadIdx.x;
  const float* e = E + (size_t)row * LB;
  float4 v[4];
#pragma unroll
  for (int c = 0; c < 4; ++c) v[c] = *(const float4*)&e[(c * 256 + tid) * 4];
  float m = -__builtin_inff();
#pragma unroll
  for (int c = 0; c < 4; ++c)
    m = fmaxf(m, fmaxf(fmaxf(v[c].x, v[c].y), fmaxf(v[c].z, v[c].w)));
#pragma unroll
  for (int o = 32; o > 0; o >>= 1) m = fmaxf(m, __shfl_down(m, o));
  if ((tid & 63) == 0) red[tid >> 6] = m;
  __syncthreads();
  m = fmaxf(fmaxf(red[0], red[1]), fmaxf(red[2], red[3]));
  float s = 0.f;
#pragma unroll
  for (int c = 0; c < 4; ++c)
    s += __expf(v[c].x - m) + __expf(v[c].y - m) + __expf(v[c].z - m) + __expf(v[c].w - m);
#pragma unroll
  for (int o = 32; o > 0; o >>= 1) s += __shfl_down(s, o);
  if ((tid & 63) == 0) red[4 + (tid >> 6)] = s;
  __syncthreads();
  if (tid == 0) rinv[row] = 1.f / (red[4] + red[5] + red[6] + red[7]);
#pragma unroll
  for (int c = 0; c < 4; ++c) {
    ushort4 w;
    w.x = f2bf(__expf(v[c].x - m));
    w.y = f2bf(__expf(v[c].y - m));
    w.z = f2bf(__expf(v[c].z - m));
    w.w = f2bf(__expf(v[c].w - m));
    *(ushort4*)&P[(size_t)row * LB + (c * 256 + tid) * 4] = w;
  }
  float4 z = {0.f, 0.f, 0.f, 0.f};
  *(float4*)&wa[(size_t)row * DD + tid * 4] = z;
}

// ---------------- column softmax stats --------------------------------------
__global__ __launch_bounds__(256) void col_partial(const float* __restrict__ E,
                                                   float* __restrict__ pmax,
                                                   float* __restrict__ psum) {
  const int c = blockIdx.x * 256 + threadIdx.x;
  const int rg = blockIdx.y;
  const float* e = E + (size_t)rg * 128 * LB + c;
  float m = -__builtin_inff(), s = 0.f;
#pragma unroll 4
  for (int r = 0; r < 128; ++r) {
    const float x = e[(size_t)r * LB];
    const float nm = fmaxf(m, x);
    s = s * __expf(m - nm) + __expf(x - nm);
    m = nm;
  }
  pmax[rg * LB + c] = m;
  psum[rg * LB + c] = s;
}

__global__ __launch_bounds__(256) void col_combine(const float* __restrict__ pmax,
                                                   const float* __restrict__ psum,
                                                   float* __restrict__ cmax,
                                                   float* __restrict__ cinv) {
  const int c = blockIdx.x * 256 + threadIdx.x;
  float m = -__builtin_inff(), s = 0.f;
#pragma unroll 4
  for (int g = 0; g < 32; ++g) {
    const float pm = pmax[g * LB + c], ps = psum[g * LB + c];
    const float nm = fmaxf(m, pm);
    s = s * __expf(m - nm) + ps * __expf(pm - nm);
    m = nm;
  }
  cmax[c] = m;
  cinv[c] = 1.f / s;
}

// ---- Pb[j][i] = bf16(exp(E[i][j] - cmax[j])), transposing ------------------
__global__ __launch_bounds__(256) void make_pb(const float* __restrict__ E,
                                               const float* __restrict__ cmax,
                                               u16* __restrict__ P) {
  __shared__ u16 t[32][33];
  const int j0 = blockIdx.x * 32;
  const int i0 = blockIdx.y * 32;
  const int tid = threadIdx.x;
  const int lr = tid >> 3, lc = (tid & 7) * 4;
  const float4 v = *(const float4*)&E[(size_t)(i0 + lr) * LB + j0 + lc];
  const float4 cm = *(const float4*)&cmax[j0 + lc];
  t[lr][lc + 0] = f2bf(__expf(v.x - cm.x));
  t[lr][lc + 1] = f2bf(__expf(v.y - cm.y));
  t[lr][lc + 2] = f2bf(__expf(v.z - cm.z));
  t[lr][lc + 3] = f2bf(__expf(v.w - cm.w));
  __syncthreads();
  ushort4 w;
  w.x = t[lc + 0][lr]; w.y = t[lc + 1][lr]; w.z = t[lc + 2][lr]; w.w = t[lc + 3][lr];
  *(ushort4*)&P[(size_t)(j0 + lr) * LA + i0 + lc] = w;
}

// ---- W[i][d] = inv[i] * sum_j P[i][j] Vt[d][j], split-K x2 -----------------
// P tile staged via global_load_lds (8KB/step); Vt fragments loaded DIRECTLY
// from global into registers (Vt is 8MB, L2/L3-hot, re-read 32x) -- halves
// the staged bytes of the staging-throughput-bound PV.
// ATOMIC=1: both K-halves unsafeAtomicAdd into pre-zeroed W0.
// ATOMIC=0: kz=0 -> W0, kz=1 -> W1 plain stores; consumer sums partials.
template <int ATOMIC>
__global__ __launch_bounds__(256) void gemm_pv(const u16* __restrict__ P,
                                               const u16* __restrict__ Vt,
                                               const float* __restrict__ inv,
                                               float* __restrict__ W0,
                                               float* __restrict__ W1) {
  __shared__ u16 lds_a[128 * 32];
  const int n0 = blockIdx.x * 128;
  const int i0 = blockIdx.y * 128;
  const int kz = blockIdx.z;
  const int tid = threadIdx.x;
  const int lane = tid & 63, quad = lane >> 4, lq = lane & 15;
  const int wave = tid >> 6;
  const int wm = (wave & 1) * 64, wn = (wave >> 1) * 64;
  f32x4 acc[4][4] = {};
  for (int t = 0; t < 64; ++t) {
    const int kt = kz * 2048 + t * 32;
    if (t) __syncthreads();
#pragma unroll
    for (int r = 0; r < 2; ++r) {
      const int chunk = wave * 128 + r * 64 + lane;
      const int row = chunk >> 2;
      const int kc = (chunk & 3) * 8;
      const int lofs = (wave * 128 + r * 64) * 16;
      async16(P + (size_t)(i0 + row) * 4096 + kt + kc, (char*)lds_a + lofs);
    }
    // direct global->reg B fragments (L2/L3-hot Vt rows)
    bf16x8 bfr[4];
#pragma unroll
    for (int f = 0; f < 4; ++f)
      bfr[f] = *(const bf16x8*)&Vt[(size_t)(n0 + wn + f * 16 + lq) * 4096 + kt + quad * 8];
    __syncthreads();
    bf16x8 af[4];
#pragma unroll
    for (int f = 0; f < 4; ++f)
      af[f] = *(const bf16x8*)&lds_a[(wm + f * 16 + lq) * 32 + quad * 8];
#pragma unroll
    for (int fm = 0; fm < 4; ++fm)
#pragma unroll
      for (int fn = 0; fn < 4; ++fn)
        acc[fm][fn] = __builtin_amdgcn_mfma_f32_16x16x32_bf16(af[fm], bfr[fn], acc[fm][fn], 0, 0, 0);
  }
  float* W = ATOMIC ? W0 : (kz ? W1 : W0);
#pragma unroll
  for (int fm = 0; fm < 4; ++fm)
#pragma unroll
    for (int r = 0; r < 4; ++r) {
      const int gm = i0 + wm + fm * 16 + quad * 4 + r;
      const float sc = inv[gm];
#pragma unroll
      for (int fn = 0; fn < 4; ++fn) {
        const int gn = n0 + wn + fn * 16 + lq;
        if (ATOMIC)
          unsafeAtomicAdd(&W[(size_t)gm * DD + gn], acc[fm][fn][r] * sc);
        else
          W[(size_t)gm * DD + gn] = acc[fm][fn][r] * sc;
      }
    }
}

// ---------------- elementwise finish (FP32 out): copy / w / a-w / a*w -------
// side b: wave = partial0 (in ob[S..2S)) + partial1 (p1); summed wave written
// back to ob[S..2S). p1 aliases ob[2S..3S) with perfect same-thread overlap.
__global__ __launch_bounds__(256) void finish(const float* __restrict__ Ain,
                                              const float* __restrict__ Bin,
                                              const float* __restrict__ p1,
                                              float* __restrict__ out) {
  const int side = blockIdx.x >> 11;
  const int blk = blockIdx.x & 2047;
  const size_t idx = ((size_t)blk * 256 + threadIdx.x) * 8;
  const size_t S = (size_t)LA * DD;
  const float* src = side ? Bin : Ain;
  float* ob = out + (size_t)side * 4 * S;
  const float4 a0 = *(const float4*)&src[idx];
  const float4 a1 = *(const float4*)&src[idx + 4];
  float4 w0 = *(const float4*)&ob[S + idx];
  float4 w1 = *(const float4*)&ob[S + idx + 4];
  if (side) {
    const float4 q0 = *(const float4*)&p1[idx];
    const float4 q1 = *(const float4*)&p1[idx + 4];
    w0.x += q0.x; w0.y += q0.y; w0.z += q0.z; w0.w += q0.w;
    w1.x += q1.x; w1.y += q1.y; w1.z += q1.z; w1.w += q1.w;
    *(float4*)&ob[S + idx] = w0;
    *(float4*)&ob[S + idx + 4] = w1;
  }
  float4 s0, s1, m0, m1;
  s0.x = a0.x - w0.x; s0.y = a0.y - w0.y; s0.z = a0.z - w0.z; s0.w = a0.w - w0.w;
  s1.x = a1.x - w1.x; s1.y = a1.y - w1.y; s1.z = a1.z - w1.z; s1.w = a1.w - w1.w;
  m0.x = a0.x * w0.x; m0.y = a0.y * w0.y; m0.z = a0.z * w0.z; m0.w = a0.w * w0.w;
  m1.x = a1.x * w1.x; m1.y = a1.y * w1.y; m1.z = a1.z * w1.z; m1.w = a1.w * w1.w;
  *(float4*)&ob[idx] = a0;            *(float4*)&ob[idx + 4] = a1;
  *(float4*)&ob[2 * S + idx] = s0;    *(float4*)&ob[2 * S + idx + 4] = s1;
  *(float4*)&ob[3 * S + idx] = m0;    *(float4*)&ob[3 * S + idx + 4] = m1;
}

extern "C" void kernel_launch(void* const* d_in, const int* in_sizes, int n_in,
                              void* d_out, int out_size, void* d_ws, size_t ws_size,
                              hipStream_t stream) {
  const float* A = (const float*)d_in[0];
  const float* B = (const float*)d_in[1];
  float* out = (float*)d_out;          // FP32 output: 8 slots of S floats
  const size_t S = (size_t)LA * DD;    // 4,194,304

  // d_ws UNUSED. Scratch choreography inside the 128 MiB fp32 out buffer:
  //   slot0: stats (1.1MB) + Bt (u16 at float-ofs 1M); finish side0 copy LAST
  //   slot1: wave_a (zeroed by row_softmax_pa, atomically accumulated)
  //   slots2-3: Ahi/Alo/Bhi/Blo (4x8MB) -> then Pa, then Pb (32MB)
  //   slots4-7: E (64MB) -> then At (slot4), wave_b p0 (slot5), p1 (slot6)
  float* pmax = out;                       // 131072
  float* psum = pmax + 131072;             // 131072
  float* rmax = psum + 131072;             // unused, layout keeper
  float* rinv = rmax + 4096;
  float* cmax = rinv + 4096;
  float* cinv = cmax + 4096;
  u16*   Bt   = (u16*)(out + 1048576);     // [DD][LB] u16, 8MB
  u16*   Ahi  = (u16*)(out + 2 * S);       // 8MB each
  u16*   Alo  = Ahi + S;
  u16*   Bhi  = Alo + S;
  u16*   Blo  = Bhi + S;
  u16*   P    = (u16*)(out + 2 * S);       // [4096][4096] u16 (after hi/lo dead)
  float* E    = out + 4 * S;               // [4096][4096] fp32, 64MB
  u16*   At   = (u16*)(out + 4 * S);       // [DD][LA] u16 (after E consumed)
  float* wave_a = out + S;
  float* wave_b = out + 5 * S;             // side-b partial 0
  float* pB1    = out + 6 * S;             // side-b partial 1

  split_ab<<<dim3(4096), 256, 0, stream>>>(A, B, Ahi, Alo, Bhi, Blo);
  gemm_energy<<<dim3(LB / 128, LA / 128), 256, 0, stream>>>(Ahi, Alo, Bhi, Blo, E);

  // row softmax + Pa in ONE E pass; also zeroes wave_a for the atomic PV
  row_softmax_pa<<<dim3(LA), 256, 0, stream>>>(E, rinv, P, wave_a);
  col_partial<<<dim3(LB / 256, 32), 256, 0, stream>>>(E, pmax, psum);
  col_combine<<<dim3(LB / 256), 256, 0, stream>>>(pmax, psum, cmax, cinv);

  // wave_a: split-K x2 atomic into pre-zeroed slot1; B-operand direct from L2
  tr_f32<<<dim3(DD / 32, LB / 32), 256, 0, stream>>>(B, Bt, LB, DD);
  gemm_pv<1><<<dim3(DD / 128, LA / 128, 2), 256, 0, stream>>>(P, Bt, rinv, wave_a, nullptr);

  // wave_b: split-K x2, two plain partials (slot5 + slot6), summed in finish
  make_pb<<<dim3(LB / 32, LA / 32), 256, 0, stream>>>(E, cmax, P);
  tr_f32<<<dim3(DD / 32, LA / 32), 256, 0, stream>>>(A, At, LA, DD);
  gemm_pv<0><<<dim3(DD / 128, LB / 128, 2), 256, 0, stream>>>(P, At, cinv, wave_b, pB1);

  finish<<<dim3(4096), 256, 0, stream>>>(A, B, pB1, out);
}

// Round 7
// 442.151 us; speedup vs baseline: 1.1790x; 1.1707x over previous
//
#include <hip/hip_runtime.h>
#include <cstdint>
#include <cstddef>

#define LA 4096
#define LB 4096
#define DD 1024

typedef unsigned short u16;
typedef short bf16x8 __attribute__((ext_vector_type(8)));
typedef float f32x4 __attribute__((ext_vector_type(4)));

__device__ __forceinline__ u16 f2bf(float f) {
  unsigned u = __builtin_bit_cast(unsigned, f);
  u += 0x7fffu + ((u >> 16) & 1u);
  return (u16)(u >> 16);
}
__device__ __forceinline__ float bf2f(u16 h) {
  return __builtin_bit_cast(float, (unsigned)h << 16);
}
// async global->LDS, 16B/lane; lds base must be wave-uniform (HW adds lane*16)
__device__ __forceinline__ void async16(const void* g, void* l) {
  __builtin_amdgcn_global_load_lds(
      (const __attribute__((address_space(1))) unsigned int*)g,
      (__attribute__((address_space(3))) unsigned int*)l, 16, 0, 0);
}

// ---- prep: split fp32 A,B -> bf16 hi/lo pairs  AND  Bt = bf16(B^T) ---------
// blocks [0,4096): split_ab work; blocks [4096,8192): 32x32 transpose of B.
__global__ __launch_bounds__(256) void prep(const float* __restrict__ A,
                                            const float* __restrict__ B,
                                            u16* __restrict__ Ahi, u16* __restrict__ Alo,
                                            u16* __restrict__ Bhi, u16* __restrict__ Blo,
                                            u16* __restrict__ Bt) {
  __shared__ u16 t[32][33];
  const int bx = blockIdx.x;
  const int tid = threadIdx.x;
  if (bx < 4096) {
    const int side = bx >> 11;
    const size_t idx = ((size_t)(bx & 2047) * 256 + tid) * 8;
    const float* src = side ? B : A;
    u16* dh = side ? Bhi : Ahi;
    u16* dl = side ? Blo : Alo;
    const float4 a = *(const float4*)&src[idx];
    const float4 b = *(const float4*)&src[idx + 4];
    float v[8] = {a.x, a.y, a.z, a.w, b.x, b.y, b.z, b.w};
    bf16x8 hi, lo;
#pragma unroll
    for (int i = 0; i < 8; ++i) {
      const u16 h = f2bf(v[i]);
      hi[i] = (short)h;
      lo[i] = (short)f2bf(v[i] - bf2f(h));
    }
    *(bf16x8*)&dh[idx] = hi;
    *(bf16x8*)&dl[idx] = lo;
  } else {
    const int blk = bx - 4096;                 // tr B [LB][DD] -> Bt [DD][LB]
    const int c0 = (blk & 31) * 32;            // DD/32 = 32 col-tiles
    const int r0 = (blk >> 5) * 32;            // LB/32 = 128 row-tiles
    const int lr = tid >> 3, lc = (tid & 7) * 4;
    const float4 v = *(const float4*)&B[(size_t)(r0 + lr) * DD + c0 + lc];
    t[lr][lc + 0] = f2bf(v.x); t[lr][lc + 1] = f2bf(v.y);
    t[lr][lc + 2] = f2bf(v.z); t[lr][lc + 3] = f2bf(v.w);
    __syncthreads();
    ushort4 w;
    w.x = t[lc + 0][lr]; w.y = t[lc + 1][lr]; w.z = t[lc + 2][lr]; w.w = t[lc + 3][lr];
    *(ushort4*)&Bt[(size_t)(c0 + lr) * LB + r0 + lc] = w;
  }
}

// ------- tiled transpose fp32 -> bf16: out[c][r] = bf16(in[r][c]) -----------
__global__ __launch_bounds__(256) void tr_f32(const float* __restrict__ in,
                                              u16* __restrict__ out,
                                              int R, int C) {
  __shared__ u16 t[32][33];
  const int c0 = blockIdx.x * 32, r0 = blockIdx.y * 32;
  const int tid = threadIdx.x;
  const int lr = tid >> 3, lc = (tid & 7) * 4;
  const float4 v = *(const float4*)&in[(size_t)(r0 + lr) * C + c0 + lc];
  t[lr][lc + 0] = f2bf(v.x); t[lr][lc + 1] = f2bf(v.y);
  t[lr][lc + 2] = f2bf(v.z); t[lr][lc + 3] = f2bf(v.w);
  __syncthreads();
  ushort4 w;
  w.x = t[lc + 0][lr]; w.y = t[lc + 1][lr]; w.z = t[lc + 2][lr]; w.w = t[lc + 3][lr];
  *(ushort4*)&out[(size_t)(c0 + lr) * R + r0 + lc] = w;
}

// ------- energy = A @ B^T, split-bf16 3-term, ASYNC staging (m97-style) -----
// Epilogue additionally emits per-(128-row-group, column) online-softmax
// partials (pmax, psum) -- each cell written by exactly ONE block, no atomics.
// This replaces the separate col_partial pass (-64MB E read, -1 launch).
__global__ __launch_bounds__(256) void gemm_energy(const u16* __restrict__ Ahi,
                                                   const u16* __restrict__ Alo,
                                                   const u16* __restrict__ Bhi,
                                                   const u16* __restrict__ Blo,
                                                   float* __restrict__ E,
                                                   float* __restrict__ pmax,
                                                   float* __restrict__ psum) {
  __shared__ u16 lah[128 * 32], lal[128 * 32], lbh[128 * 32], lbl[128 * 32];
  __shared__ float cred[4][4][16][2];
  const int j0 = blockIdx.x * 128;
  const int i0 = blockIdx.y * 128;
  const int tid = threadIdx.x;
  const int lane = tid & 63, quad = lane >> 4, lq = lane & 15;
  const int wave = tid >> 6;
  const int wm = (wave & 1) * 64, wn = (wave >> 1) * 64;
  f32x4 acc[4][4] = {};
  for (int kt = 0; kt < DD; kt += 32) {
    if (kt) __syncthreads();
#pragma unroll
    for (int r = 0; r < 2; ++r) {
      const int chunk = wave * 128 + r * 64 + lane;
      const int row = chunk >> 2;
      const int kc = (chunk & 3) * 8;
      const int lofs = (wave * 128 + r * 64) * 16;
      const size_t ga = (size_t)(i0 + row) * DD + kt + kc;
      const size_t gb = (size_t)(j0 + row) * DD + kt + kc;
      async16(Ahi + ga, (char*)lah + lofs);
      async16(Alo + ga, (char*)lal + lofs);
      async16(Bhi + gb, (char*)lbh + lofs);
      async16(Blo + gb, (char*)lbl + lofs);
    }
    __syncthreads();
    bf16x8 fah[4], fal[4], fbh[4], fbl[4];
#pragma unroll
    for (int f = 0; f < 4; ++f) {
      fah[f] = *(const bf16x8*)&lah[(wm + f * 16 + lq) * 32 + quad * 8];
      fal[f] = *(const bf16x8*)&lal[(wm + f * 16 + lq) * 32 + quad * 8];
      fbh[f] = *(const bf16x8*)&lbh[(wn + f * 16 + lq) * 32 + quad * 8];
      fbl[f] = *(const bf16x8*)&lbl[(wn + f * 16 + lq) * 32 + quad * 8];
    }
#pragma unroll
    for (int fm = 0; fm < 4; ++fm)
#pragma unroll
      for (int fn = 0; fn < 4; ++fn) {
        acc[fm][fn] = __builtin_amdgcn_mfma_f32_16x16x32_bf16(fal[fm], fbh[fn], acc[fm][fn], 0, 0, 0);
        acc[fm][fn] = __builtin_amdgcn_mfma_f32_16x16x32_bf16(fah[fm], fbl[fn], acc[fm][fn], 0, 0, 0);
        acc[fm][fn] = __builtin_amdgcn_mfma_f32_16x16x32_bf16(fah[fm], fbh[fn], acc[fm][fn], 0, 0, 0);
      }
  }
#pragma unroll
  for (int fm = 0; fm < 4; ++fm)
#pragma unroll
    for (int fn = 0; fn < 4; ++fn)
#pragma unroll
      for (int r = 0; r < 4; ++r) {
        const int gi = i0 + wm + fm * 16 + quad * 4 + r;
        const int gj = j0 + wn + fn * 16 + lq;
        E[(size_t)gi * LB + gj] = acc[fm][fn][r];
      }
  // ---- fused column-softmax partials for this 128x128 tile -----------------
  const int rg = i0 >> 7;
#pragma unroll
  for (int fn = 0; fn < 4; ++fn) {
    float m = acc[0][fn][0];
#pragma unroll
    for (int fm = 0; fm < 4; ++fm)
#pragma unroll
      for (int r = 0; r < 4; ++r) m = fmaxf(m, acc[fm][fn][r]);
    float s = 0.f;
#pragma unroll
    for (int fm = 0; fm < 4; ++fm)
#pragma unroll
      for (int r = 0; r < 4; ++r) s += __expf(acc[fm][fn][r] - m);
#pragma unroll
    for (int mask = 16; mask <= 32; mask <<= 1) {
      const float om = __shfl_xor(m, mask);
      const float os = __shfl_xor(s, mask);
      const float nm = fmaxf(m, om);
      s = s * __expf(m - nm) + os * __expf(om - nm);
      m = nm;
    }
    if (quad == 0) { cred[wave][fn][lq][0] = m; cred[wave][fn][lq][1] = s; }
  }
  __syncthreads();
  if ((wave & 1) == 0 && quad == 0) {   // waves 0 (wn=0) and 2 (wn=64)
#pragma unroll
    for (int fn = 0; fn < 4; ++fn) {
      const float m1 = cred[wave][fn][lq][0], s1 = cred[wave][fn][lq][1];
      const float m2 = cred[wave + 1][fn][lq][0], s2 = cred[wave + 1][fn][lq][1];
      const float nm = fmaxf(m1, m2);
      const float s = s1 * __expf(m1 - nm) + s2 * __expf(m2 - nm);
      const int c = j0 + wn + fn * 16 + lq;
      pmax[rg * LB + c] = nm;
      psum[rg * LB + c] = s;
    }
  }
}

// ---- fused: row softmax stats + Pa[i][j]=bf16(exp(E-rmax)) + zero wave_a ---
__global__ __launch_bounds__(256) void row_softmax_pa(const float* __restrict__ E,
                                                      float* __restrict__ rinv,
                                                      u16* __restrict__ P,
                                                      float* __restrict__ wa) {
  __shared__ float red[8];
  const int row = blockIdx.x, tid = threadIdx.x;
  const float* e = E + (size_t)row * LB;
  float4 v[4];
#pragma unroll
  for (int c = 0; c < 4; ++c) v[c] = *(const float4*)&e[(c * 256 + tid) * 4];
  float m = -__builtin_inff();
#pragma unroll
  for (int c = 0; c < 4; ++c)
    m = fmaxf(m, fmaxf(fmaxf(v[c].x, v[c].y), fmaxf(v[c].z, v[c].w)));
#pragma unroll
  for (int o = 32; o > 0; o >>= 1) m = fmaxf(m, __shfl_down(m, o));
  if ((tid & 63) == 0) red[tid >> 6] = m;
  __syncthreads();
  m = fmaxf(fmaxf(red[0], red[1]), fmaxf(red[2], red[3]));
  float s = 0.f;
#pragma unroll
  for (int c = 0; c < 4; ++c)
    s += __expf(v[c].x - m) + __expf(v[c].y - m) + __expf(v[c].z - m) + __expf(v[c].w - m);
#pragma unroll
  for (int o = 32; o > 0; o >>= 1) s += __shfl_down(s, o);
  if ((tid & 63) == 0) red[4 + (tid >> 6)] = s;
  __syncthreads();
  if (tid == 0) rinv[row] = 1.f / (red[4] + red[5] + red[6] + red[7]);
#pragma unroll
  for (int c = 0; c < 4; ++c) {
    ushort4 w;
    w.x = f2bf(__expf(v[c].x - m));
    w.y = f2bf(__expf(v[c].y - m));
    w.z = f2bf(__expf(v[c].z - m));
    w.w = f2bf(__expf(v[c].w - m));
    *(ushort4*)&P[(size_t)row * LB + (c * 256 + tid) * 4] = w;
  }
  float4 z = {0.f, 0.f, 0.f, 0.f};
  *(float4*)&wa[(size_t)row * DD + tid * 4] = z;
}

// ---------------- column softmax combine ------------------------------------
__global__ __launch_bounds__(256) void col_combine(const float* __restrict__ pmax,
                                                   const float* __restrict__ psum,
                                                   float* __restrict__ cmax,
                                                   float* __restrict__ cinv) {
  const int c = blockIdx.x * 256 + threadIdx.x;
  float m = -__builtin_inff(), s = 0.f;
#pragma unroll 4
  for (int g = 0; g < 32; ++g) {
    const float pm = pmax[g * LB + c], ps = psum[g * LB + c];
    const float nm = fmaxf(m, pm);
    s = s * __expf(m - nm) + ps * __expf(pm - nm);
    m = nm;
  }
  cmax[c] = m;
  cinv[c] = 1.f / s;
}

// ---- Pb[j][i] = bf16(exp(E[i][j] - cmax[j])), transposing ------------------
__global__ __launch_bounds__(256) void make_pb(const float* __restrict__ E,
                                               const float* __restrict__ cmax,
                                               u16* __restrict__ P) {
  __shared__ u16 t[32][33];
  const int j0 = blockIdx.x * 32;
  const int i0 = blockIdx.y * 32;
  const int tid = threadIdx.x;
  const int lr = tid >> 3, lc = (tid & 7) * 4;
  const float4 v = *(const float4*)&E[(size_t)(i0 + lr) * LB + j0 + lc];
  const float4 cm = *(const float4*)&cmax[j0 + lc];
  t[lr][lc + 0] = f2bf(__expf(v.x - cm.x));
  t[lr][lc + 1] = f2bf(__expf(v.y - cm.y));
  t[lr][lc + 2] = f2bf(__expf(v.z - cm.z));
  t[lr][lc + 3] = f2bf(__expf(v.w - cm.w));
  __syncthreads();
  ushort4 w;
  w.x = t[lc + 0][lr]; w.y = t[lc + 1][lr]; w.z = t[lc + 2][lr]; w.w = t[lc + 3][lr];
  *(ushort4*)&P[(size_t)(j0 + lr) * LA + i0 + lc] = w;
}

// ---- W[i][d] = inv[i] * sum_j P[i][j] Vt[d][j], split-K x2 -----------------
// ATOMIC=1: both K-halves unsafeAtomicAdd into pre-zeroed W0.
// ATOMIC=0: kz=0 -> W0, kz=1 -> W1 plain stores; consumer sums partials.
template <int ATOMIC>
__global__ __launch_bounds__(256) void gemm_pv(const u16* __restrict__ P,
                                               const u16* __restrict__ Vt,
                                               const float* __restrict__ inv,
                                               float* __restrict__ W0,
                                               float* __restrict__ W1) {
  __shared__ u16 lds_a[128 * 32];
  __shared__ u16 lds_b[128 * 32];
  const int n0 = blockIdx.x * 128;
  const int i0 = blockIdx.y * 128;
  const int kz = blockIdx.z;
  const int tid = threadIdx.x;
  const int lane = tid & 63, quad = lane >> 4, lq = lane & 15;
  const int wave = tid >> 6;
  const int wm = (wave & 1) * 64, wn = (wave >> 1) * 64;
  f32x4 acc[4][4] = {};
  for (int t = 0; t < 64; ++t) {
    const int kt = kz * 2048 + t * 32;
    if (t) __syncthreads();
#pragma unroll
    for (int r = 0; r < 2; ++r) {
      const int chunk = wave * 128 + r * 64 + lane;
      const int row = chunk >> 2;
      const int kc = (chunk & 3) * 8;
      const int lofs = (wave * 128 + r * 64) * 16;
      async16(P + (size_t)(i0 + row) * 4096 + kt + kc, (char*)lds_a + lofs);
      async16(Vt + (size_t)(n0 + row) * 4096 + kt + kc, (char*)lds_b + lofs);
    }
    __syncthreads();
    bf16x8 af[4], bfr[4];
#pragma unroll
    for (int f = 0; f < 4; ++f) {
      af[f]  = *(const bf16x8*)&lds_a[(wm + f * 16 + lq) * 32 + quad * 8];
      bfr[f] = *(const bf16x8*)&lds_b[(wn + f * 16 + lq) * 32 + quad * 8];
    }
#pragma unroll
    for (int fm = 0; fm < 4; ++fm)
#pragma unroll
      for (int fn = 0; fn < 4; ++fn)
        acc[fm][fn] = __builtin_amdgcn_mfma_f32_16x16x32_bf16(af[fm], bfr[fn], acc[fm][fn], 0, 0, 0);
  }
  float* W = ATOMIC ? W0 : (kz ? W1 : W0);
#pragma unroll
  for (int fm = 0; fm < 4; ++fm)
#pragma unroll
    for (int r = 0; r < 4; ++r) {
      const int gm = i0 + wm + fm * 16 + quad * 4 + r;
      const float sc = inv[gm];
#pragma unroll
      for (int fn = 0; fn < 4; ++fn) {
        const int gn = n0 + wn + fn * 16 + lq;
        if (ATOMIC)
          unsafeAtomicAdd(&W[(size_t)gm * DD + gn], acc[fm][fn][r] * sc);
        else
          W[(size_t)gm * DD + gn] = acc[fm][fn][r] * sc;
      }
    }
}

// ---------------- elementwise finish (FP32 out): copy / w / a-w / a*w -------
// side b: wave = partial0 (in ob[S..2S)) + partial1 (p1); summed wave written
// back to ob[S..2S). p1 aliases ob[2S..3S) with perfect same-thread overlap.
__global__ __launch_bounds__(256) void finish(const float* __restrict__ Ain,
                                              const float* __restrict__ Bin,
                                              const float* __restrict__ p1,
                                              float* __restrict__ out) {
  const int side = blockIdx.x >> 11;
  const int blk = blockIdx.x & 2047;
  const size_t idx = ((size_t)blk * 256 + threadIdx.x) * 8;
  const size_t S = (size_t)LA * DD;
  const float* src = side ? Bin : Ain;
  float* ob = out + (size_t)side * 4 * S;
  const float4 a0 = *(const float4*)&src[idx];
  const float4 a1 = *(const float4*)&src[idx + 4];
  float4 w0 = *(const float4*)&ob[S + idx];
  float4 w1 = *(const float4*)&ob[S + idx + 4];
  if (side) {
    const float4 q0 = *(const float4*)&p1[idx];
    const float4 q1 = *(const float4*)&p1[idx + 4];
    w0.x += q0.x; w0.y += q0.y; w0.z += q0.z; w0.w += q0.w;
    w1.x += q1.x; w1.y += q1.y; w1.z += q1.z; w1.w += q1.w;
    *(float4*)&ob[S + idx] = w0;
    *(float4*)&ob[S + idx + 4] = w1;
  }
  float4 s0, s1, m0, m1;
  s0.x = a0.x - w0.x; s0.y = a0.y - w0.y; s0.z = a0.z - w0.z; s0.w = a0.w - w0.w;
  s1.x = a1.x - w1.x; s1.y = a1.y - w1.y; s1.z = a1.z - w1.z; s1.w = a1.w - w1.w;
  m0.x = a0.x * w0.x; m0.y = a0.y * w0.y; m0.z = a0.z * w0.z; m0.w = a0.w * w0.w;
  m1.x = a1.x * w1.x; m1.y = a1.y * w1.y; m1.z = a1.z * w1.z; m1.w = a1.w * w1.w;
  *(float4*)&ob[idx] = a0;            *(float4*)&ob[idx + 4] = a1;
  *(float4*)&ob[2 * S + idx] = s0;    *(float4*)&ob[2 * S + idx + 4] = s1;
  *(float4*)&ob[3 * S + idx] = m0;    *(float4*)&ob[3 * S + idx + 4] = m1;
}

extern "C" void kernel_launch(void* const* d_in, const int* in_sizes, int n_in,
                              void* d_out, int out_size, void* d_ws, size_t ws_size,
                              hipStream_t stream) {
  const float* A = (const float*)d_in[0];
  const float* B = (const float*)d_in[1];
  float* out = (float*)d_out;          // FP32 output: 8 slots of S floats
  const size_t S = (size_t)LA * DD;    // 4,194,304

  // d_ws UNUSED. Scratch choreography inside the 128 MiB fp32 out buffer:
  //   slot0: stats (1.1MB) + Bt (u16 at float-ofs 1M); finish side0 copy LAST
  //   slot1: wave_a (zeroed by row_softmax_pa, atomically accumulated)
  //   slots2-3: Ahi/Alo/Bhi/Blo (4x8MB) -> then Pa, then Pb (32MB)
  //   slots4-7: E (64MB) -> then At (slot4), wave_b p0 (slot5), p1 (slot6)
  float* pmax = out;                       // 131072
  float* psum = pmax + 131072;             // 131072
  float* rmax = psum + 131072;             // unused, layout keeper
  float* rinv = rmax + 4096;
  float* cmax = rinv + 4096;
  float* cinv = cmax + 4096;
  u16*   Bt   = (u16*)(out + 1048576);     // [DD][LB] u16, 8MB
  u16*   Ahi  = (u16*)(out + 2 * S);       // 8MB each
  u16*   Alo  = Ahi + S;
  u16*   Bhi  = Alo + S;
  u16*   Blo  = Bhi + S;
  u16*   P    = (u16*)(out + 2 * S);       // [4096][4096] u16 (after hi/lo dead)
  float* E    = out + 4 * S;               // [4096][4096] fp32, 64MB
  u16*   At   = (u16*)(out + 4 * S);       // [DD][LA] u16 (after E consumed)
  float* wave_a = out + S;
  float* wave_b = out + 5 * S;             // side-b partial 0
  float* pB1    = out + 6 * S;             // side-b partial 1

  // split A/B + transpose B in one launch
  prep<<<dim3(8192), 256, 0, stream>>>(A, B, Ahi, Alo, Bhi, Blo, Bt);

  // energy GEMM + fused column-softmax partials
  gemm_energy<<<dim3(LB / 128, LA / 128), 256, 0, stream>>>(Ahi, Alo, Bhi, Blo, E, pmax, psum);

  // row softmax + Pa in ONE E pass; also zeroes wave_a for the atomic PV
  row_softmax_pa<<<dim3(LA), 256, 0, stream>>>(E, rinv, P, wave_a);
  col_combine<<<dim3(LB / 256), 256, 0, stream>>>(pmax, psum, cmax, cinv);

  // wave_a: split-K x2 atomic into pre-zeroed slot1
  gemm_pv<1><<<dim3(DD / 128, LA / 128, 2), 256, 0, stream>>>(P, Bt, rinv, wave_a, nullptr);

  // wave_b: split-K x2, two plain partials (slot5 + slot6), summed in finish
  make_pb<<<dim3(LB / 32, LA / 32), 256, 0, stream>>>(E, cmax, P);
  tr_f32<<<dim3(DD / 32, LA / 32), 256, 0, stream>>>(A, At, LA, DD);
  gemm_pv<0><<<dim3(DD / 128, LB / 128, 2), 256, 0, stream>>>(P, At, cinv, wave_b, pB1);

  finish<<<dim3(4096), 256, 0, stream>>>(A, B, pB1, out);
}

// Round 8
// 439.965 us; speedup vs baseline: 1.1849x; 1.0050x over previous
//
#include <hip/hip_runtime.h>
#include <cstdint>
#include <cstddef>

#define LA 4096
#define LB 4096
#define DD 1024

typedef unsigned short u16;
typedef short bf16x8 __attribute__((ext_vector_type(8)));
typedef float f32x4 __attribute__((ext_vector_type(4)));

__device__ __forceinline__ u16 f2bf(float f) {
  unsigned u = __builtin_bit_cast(unsigned, f);
  u += 0x7fffu + ((u >> 16) & 1u);
  return (u16)(u >> 16);
}
__device__ __forceinline__ float bf2f(u16 h) {
  return __builtin_bit_cast(float, (unsigned)h << 16);
}
// async global->LDS, 16B/lane; lds base must be wave-uniform (HW adds lane*16)
__device__ __forceinline__ void async16(const void* g, void* l) {
  __builtin_amdgcn_global_load_lds(
      (const __attribute__((address_space(1))) unsigned int*)g,
      (__attribute__((address_space(3))) unsigned int*)l, 16, 0, 0);
}

// ---- prep: split fp32 A,B -> concat-K bf16 (A'=[hi|hi|lo], B'=[hi|lo|hi])
//      AND Bt = bf16(B^T).  blocks [0,4096): split; [4096,8192): transpose.
__global__ __launch_bounds__(256) void prep(const float* __restrict__ A,
                                            const float* __restrict__ B,
                                            u16* __restrict__ Ap,
                                            u16* __restrict__ Bp,
                                            u16* __restrict__ Bt) {
  __shared__ u16 t[32][33];
  const int bx = blockIdx.x;
  const int tid = threadIdx.x;
  if (bx < 4096) {
    const int side = bx >> 11;
    const size_t idx = ((size_t)(bx & 2047) * 256 + tid) * 8;
    const float* src = side ? B : A;
    u16* dst = side ? Bp : Ap;
    const float4 a = *(const float4*)&src[idx];
    const float4 b = *(const float4*)&src[idx + 4];
    float v[8] = {a.x, a.y, a.z, a.w, b.x, b.y, b.z, b.w};
    bf16x8 hi, lo;
#pragma unroll
    for (int i = 0; i < 8; ++i) {
      const u16 h = f2bf(v[i]);
      hi[i] = (short)h;
      lo[i] = (short)f2bf(v[i] - bf2f(h));
    }
    const size_t row = idx >> 10;
    const size_t k = idx & 1023;
    u16* base = dst + row * 3072 + k;
    *(bf16x8*)&base[0] = hi;
    *(bf16x8*)&base[side ? 2048 : 1024] = hi;
    *(bf16x8*)&base[side ? 1024 : 2048] = lo;
  } else {
    const int blk = bx - 4096;                 // tr B [LB][DD] -> Bt [DD][LB]
    const int c0 = (blk & 31) * 32;
    const int r0 = (blk >> 5) * 32;
    const int lr = tid >> 3, lc = (tid & 7) * 4;
    const float4 v = *(const float4*)&B[(size_t)(r0 + lr) * DD + c0 + lc];
    t[lr][lc + 0] = f2bf(v.x); t[lr][lc + 1] = f2bf(v.y);
    t[lr][lc + 2] = f2bf(v.z); t[lr][lc + 3] = f2bf(v.w);
    __syncthreads();
    ushort4 w;
    w.x = t[lc + 0][lr]; w.y = t[lc + 1][lr]; w.z = t[lc + 2][lr]; w.w = t[lc + 3][lr];
    *(ushort4*)&Bt[(size_t)(c0 + lr) * LB + r0 + lc] = w;
  }
}

// ------- tiled transpose fp32 -> bf16: out[c][r] = bf16(in[r][c]) -----------
__global__ __launch_bounds__(256) void tr_f32(const float* __restrict__ in,
                                              u16* __restrict__ out,
                                              int R, int C) {
  __shared__ u16 t[32][33];
  const int c0 = blockIdx.x * 32, r0 = blockIdx.y * 32;
  const int tid = threadIdx.x;
  const int lr = tid >> 3, lc = (tid & 7) * 4;
  const float4 v = *(const float4*)&in[(size_t)(r0 + lr) * C + c0 + lc];
  t[lr][lc + 0] = f2bf(v.x); t[lr][lc + 1] = f2bf(v.y);
  t[lr][lc + 2] = f2bf(v.z); t[lr][lc + 3] = f2bf(v.w);
  __syncthreads();
  ushort4 w;
  w.x = t[lc + 0][lr]; w.y = t[lc + 1][lr]; w.z = t[lc + 2][lr]; w.w = t[lc + 3][lr];
  *(ushort4*)&out[(size_t)(c0 + lr) * R + r0 + lc] = w;
}

// ======== energy: 256x256 8-phase GEMM (m201 template), K=3072 concat ======
// E = Ap . Bp^T (row-major [4096][3072] bf16 each). 8 waves (2Mx4N), BK=64,
// LDS 128KiB = 2buf x {A,B} x 2 half-tiles[128][64]. Per K-tile 4 phases:
// quadrant = (m-half x fn-half); per phase: ds_read frags || stage 1 half-tile
// -> s_barrier -> lgkmcnt(0) -> setprio(1) 16 MFMA setprio(0) -> s_barrier.
// vmcnt(6) once per tile (phase 3); stage stream per tile: B0,B1,A0,A1.
// st_16x32 swizzle: LDS linear dest + pre-swizzled global src + swz ds_read.
// Fused col-softmax partials: each wave owns one full 128-row group.
#define NTILES 48

#define STAGE(M, h, tt)                                                      \
  do {                                                                       \
    if ((tt) < NTILES) {                                                     \
      u16* lb = &lds[(tt) & 1][M][h][0];                                     \
      async16(gsrc[M][h][0] + (tt) * 128, lb + ldst0);                       \
      async16(gsrc[M][h][1] + (tt) * 128, lb + ldst1);                       \
    }                                                                        \
  } while (0)

#define LDA(mbase)                                                           \
  _Pragma("unroll") for (int m = 0; m < 4; ++m)                              \
  _Pragma("unroll") for (int ks = 0; ks < 2; ++ks) {                         \
    const int row = (mbase + m) * 16 + lq;                                   \
    const int cb = (ks * 64 + quad * 16) ^ (((row >> 2) & 1) << 5);          \
    af[m][ks] = *(const bf16x8*)&lds[p][0][wr][row * 64 + (cb >> 1)];        \
  }

#define LDB(arr, fbase)                                                      \
  _Pragma("unroll") for (int f = 0; f < 2; ++f)                              \
  _Pragma("unroll") for (int ks = 0; ks < 2; ++ks) {                         \
    const int row = (wc & 1) * 64 + (fbase + f) * 16 + lq;                   \
    const int cb = (ks * 64 + quad * 16) ^ (((row >> 2) & 1) << 5);          \
    arr[f][ks] = *(const bf16x8*)&lds[p][1][wc >> 1][row * 64 + (cb >> 1)];  \
  }

#define MM(mbase, fbase, barr)                                               \
  __builtin_amdgcn_s_setprio(1);                                             \
  _Pragma("unroll") for (int m = 0; m < 4; ++m)                              \
  _Pragma("unroll") for (int f = 0; f < 2; ++f)                              \
  _Pragma("unroll") for (int ks = 0; ks < 2; ++ks)                           \
    acc[mbase + m][fbase + f] = __builtin_amdgcn_mfma_f32_16x16x32_bf16(     \
        af[m][ks], barr[f][ks], acc[mbase + m][fbase + f], 0, 0, 0);         \
  __builtin_amdgcn_s_setprio(0);

#define SBAR __builtin_amdgcn_s_barrier()
#define SCHB __builtin_amdgcn_sched_barrier(0)
#define LGKM0 asm volatile("s_waitcnt lgkmcnt(0)" ::: "memory")

__global__ __launch_bounds__(512, 2) void gemm8ph(const u16* __restrict__ Ap,
                                                  const u16* __restrict__ Bp,
                                                  float* __restrict__ E,
                                                  float* __restrict__ pmax,
                                                  float* __restrict__ psum) {
  __shared__ u16 lds[2][2][2][8192];   // [buf][mat][half][128*64]
  const int tid = threadIdx.x;
  const int lane = tid & 63, quad = lane >> 4, lq = lane & 15;
  const int wave = tid >> 6;
  const int wr = wave >> 2, wc = wave & 3;
  int lin = blockIdx.y * 16 + blockIdx.x;
  lin = (lin & 7) * 32 + (lin >> 3);           // XCD-bijective (256 % 8 == 0)
  const int j0 = (lin & 15) * 256;
  const int i0 = (lin >> 4) * 256;

  // staging source precompute: linear LDS dest + inverse-swizzled global src
  const char* gsrc[2][2][2];                    // [mat][half][r] literal-only
  int ldst0, ldst1;
  {
    const int db0 = tid * 16, db1 = 8192 + tid * 16;
    const int dr0 = db0 >> 7, dr1 = db1 >> 7;
    const int sc0 = (db0 & 127) ^ (((dr0 >> 2) & 1) << 5);
    const int sc1 = (db1 & 127) ^ (((dr1 >> 2) & 1) << 5);
    ldst0 = wave * 512;
    ldst1 = 4096 + wave * 512;
#pragma unroll
    for (int M = 0; M < 2; ++M)
#pragma unroll
      for (int h = 0; h < 2; ++h) {
        const char* base = (const char*)(M ? Bp : Ap);
        const int rb = (M ? j0 : i0) + h * 128;
        gsrc[M][h][0] = base + (size_t)(rb + dr0) * 6144 + sc0;
        gsrc[M][h][1] = base + (size_t)(rb + dr1) * 6144 + sc1;
      }
  }

  f32x4 acc[8][4] = {};
  bf16x8 af[4][2], bf0[2][2], bf1[2][2];

  // prologue: tile0 B0,B1,A0,A1 ; vmcnt(4) ; tile1 B0,B1,A0 ; vmcnt(6)
  STAGE(1, 0, 0); STAGE(1, 1, 0); STAGE(0, 0, 0); STAGE(0, 1, 0);
  asm volatile("s_waitcnt vmcnt(4)" ::: "memory");
  STAGE(1, 0, 1); STAGE(1, 1, 1); STAGE(0, 0, 1);
  asm volatile("s_waitcnt vmcnt(6)" ::: "memory");
  SBAR;

  for (int t = 0; t < NTILES; ++t) {
    const int p = t & 1;
    // phase 0: A m0-3 + B fn0-1 ; stage (t+1).A1 ; MFMA mh0/fh0
    SCHB;
    LDA(0); LDB(bf0, 0);
    STAGE(0, 1, t + 1);
    SCHB; SBAR; LGKM0; SCHB;
    MM(0, 0, bf0);
    SCHB; SBAR;
    // phase 1: B fn2-3 ; stage (t+2).B0 ; MFMA mh0/fh1
    SCHB;
    LDB(bf1, 2);
    STAGE(1, 0, t + 2);
    SCHB; SBAR; LGKM0; SCHB;
    MM(0, 2, bf1);
    SCHB; SBAR;
    // phase 2: A m4-7 ; stage (t+2).B1 ; MFMA mh1/fh0
    SCHB;
    LDA(4);
    STAGE(1, 1, t + 2);
    SCHB; SBAR; LGKM0; SCHB;
    MM(4, 0, bf0);
    SCHB; SBAR;
    // phase 3: stage (t+2).A0 ; MFMA mh1/fh1 ; vmcnt(6)
    SCHB;
    STAGE(0, 0, t + 2);
    SCHB; SBAR; LGKM0; SCHB;
    MM(4, 2, bf1);
    SCHB;
    asm volatile("s_waitcnt vmcnt(6)" ::: "memory");
    SBAR;
  }

  // epilogue: E write + fused col-softmax partials (1 writer per cell)
  const int rbase = i0 + wr * 128;
  const int cbase = j0 + wc * 64;
#pragma unroll
  for (int fm = 0; fm < 8; ++fm)
#pragma unroll
    for (int fn = 0; fn < 4; ++fn)
#pragma unroll
      for (int r = 0; r < 4; ++r)
        E[(size_t)(rbase + fm * 16 + quad * 4 + r) * LB + cbase + fn * 16 + lq] =
            acc[fm][fn][r];
  const int rg = (i0 >> 7) + wr;               // this wave's 128-row group
#pragma unroll
  for (int fn = 0; fn < 4; ++fn) {
    float m = acc[0][fn][0];
#pragma unroll
    for (int fm = 0; fm < 8; ++fm)
#pragma unroll
      for (int r = 0; r < 4; ++r) m = fmaxf(m, acc[fm][fn][r]);
    float s = 0.f;
#pragma unroll
    for (int fm = 0; fm < 8; ++fm)
#pragma unroll
      for (int r = 0; r < 4; ++r) s += __expf(acc[fm][fn][r] - m);
#pragma unroll
    for (int mask = 16; mask <= 32; mask <<= 1) {
      const float om = __shfl_xor(m, mask);
      const float os = __shfl_xor(s, mask);
      const float nm = fmaxf(m, om);
      s = s * __expf(m - nm) + os * __expf(om - nm);
      m = nm;
    }
    if (quad == 0) {
      pmax[rg * LB + cbase + fn * 16 + lq] = m;
      psum[rg * LB + cbase + fn * 16 + lq] = s;
    }
  }
}

// ---- fused: row softmax stats + Pa[i][j]=bf16(exp(E-rmax)) + zero wave_a ---
__global__ __launch_bounds__(256) void row_softmax_pa(const float* __restrict__ E,
                                                      float* __restrict__ rinv,
                                                      u16* __restrict__ P,
                                                      float* __restrict__ wa) {
  __shared__ float red[8];
  const int row = blockIdx.x, tid = threadIdx.x;
  const float* e = E + (size_t)row * LB;
  float4 v[4];
#pragma unroll
  for (int c = 0; c < 4; ++c) v[c] = *(const float4*)&e[(c * 256 + tid) * 4];
  float m = -__builtin_inff();
#pragma unroll
  for (int c = 0; c < 4; ++c)
    m = fmaxf(m, fmaxf(fmaxf(v[c].x, v[c].y), fmaxf(v[c].z, v[c].w)));
#pragma unroll
  for (int o = 32; o > 0; o >>= 1) m = fmaxf(m, __shfl_down(m, o));
  if ((tid & 63) == 0) red[tid >> 6] = m;
  __syncthreads();
  m = fmaxf(fmaxf(red[0], red[1]), fmaxf(red[2], red[3]));
  float s = 0.f;
#pragma unroll
  for (int c = 0; c < 4; ++c)
    s += __expf(v[c].x - m) + __expf(v[c].y - m) + __expf(v[c].z - m) + __expf(v[c].w - m);
#pragma unroll
  for (int o = 32; o > 0; o >>= 1) s += __shfl_down(s, o);
  if ((tid & 63) == 0) red[4 + (tid >> 6)] = s;
  __syncthreads();
  if (tid == 0) rinv[row] = 1.f / (red[4] + red[5] + red[6] + red[7]);
#pragma unroll
  for (int c = 0; c < 4; ++c) {
    ushort4 w;
    w.x = f2bf(__expf(v[c].x - m));
    w.y = f2bf(__expf(v[c].y - m));
    w.z = f2bf(__expf(v[c].z - m));
    w.w = f2bf(__expf(v[c].w - m));
    *(ushort4*)&P[(size_t)row * LB + (c * 256 + tid) * 4] = w;
  }
  float4 z = {0.f, 0.f, 0.f, 0.f};
  *(float4*)&wa[(size_t)row * DD + tid * 4] = z;
}

// ---------------- column softmax combine ------------------------------------
__global__ __launch_bounds__(256) void col_combine(const float* __restrict__ pmax,
                                                   const float* __restrict__ psum,
                                                   float* __restrict__ cmax,
                                                   float* __restrict__ cinv) {
  const int c = blockIdx.x * 256 + threadIdx.x;
  float m = -__builtin_inff(), s = 0.f;
#pragma unroll 4
  for (int g = 0; g < 32; ++g) {
    const float pm = pmax[g * LB + c], ps = psum[g * LB + c];
    const float nm = fmaxf(m, pm);
    s = s * __expf(m - nm) + ps * __expf(pm - nm);
    m = nm;
  }
  cmax[c] = m;
  cinv[c] = 1.f / s;
}

// ---- Pb[j][i] = bf16(exp(E[i][j] - cmax[j])), transposing ------------------
__global__ __launch_bounds__(256) void make_pb(const float* __restrict__ E,
                                               const float* __restrict__ cmax,
                                               u16* __restrict__ P) {
  __shared__ u16 t[32][33];
  const int j0 = blockIdx.x * 32;
  const int i0 = blockIdx.y * 32;
  const int tid = threadIdx.x;
  const int lr = tid >> 3, lc = (tid & 7) * 4;
  const float4 v = *(const float4*)&E[(size_t)(i0 + lr) * LB + j0 + lc];
  const float4 cm = *(const float4*)&cmax[j0 + lc];
  t[lr][lc + 0] = f2bf(__expf(v.x - cm.x));
  t[lr][lc + 1] = f2bf(__expf(v.y - cm.y));
  t[lr][lc + 2] = f2bf(__expf(v.z - cm.z));
  t[lr][lc + 3] = f2bf(__expf(v.w - cm.w));
  __syncthreads();
  ushort4 w;
  w.x = t[lc + 0][lr]; w.y = t[lc + 1][lr]; w.z = t[lc + 2][lr]; w.w = t[lc + 3][lr];
  *(ushort4*)&P[(size_t)(j0 + lr) * LA + i0 + lc] = w;
}

// ---- W[i][d] = inv[i] * sum_j P[i][j] Vt[d][j], split-K x2 -----------------
template <int ATOMIC>
__global__ __launch_bounds__(256) void gemm_pv(const u16* __restrict__ P,
                                               const u16* __restrict__ Vt,
                                               const float* __restrict__ inv,
                                               float* __restrict__ W0,
                                               float* __restrict__ W1) {
  __shared__ u16 lds_a[128 * 32];
  __shared__ u16 lds_b[128 * 32];
  const int n0 = blockIdx.x * 128;
  const int i0 = blockIdx.y * 128;
  const int kz = blockIdx.z;
  const int tid = threadIdx.x;
  const int lane = tid & 63, quad = lane >> 4, lq = lane & 15;
  const int wave = tid >> 6;
  const int wm = (wave & 1) * 64, wn = (wave >> 1) * 64;
  f32x4 acc[4][4] = {};
  for (int t = 0; t < 64; ++t) {
    const int kt = kz * 2048 + t * 32;
    if (t) __syncthreads();
#pragma unroll
    for (int r = 0; r < 2; ++r) {
      const int chunk = wave * 128 + r * 64 + lane;
      const int row = chunk >> 2;
      const int kc = (chunk & 3) * 8;
      const int lofs = (wave * 128 + r * 64) * 16;
      async16(P + (size_t)(i0 + row) * 4096 + kt + kc, (char*)lds_a + lofs);
      async16(Vt + (size_t)(n0 + row) * 4096 + kt + kc, (char*)lds_b + lofs);
    }
    __syncthreads();
    bf16x8 af[4], bfr[4];
#pragma unroll
    for (int f = 0; f < 4; ++f) {
      af[f]  = *(const bf16x8*)&lds_a[(wm + f * 16 + lq) * 32 + quad * 8];
      bfr[f] = *(const bf16x8*)&lds_b[(wn + f * 16 + lq) * 32 + quad * 8];
    }
#pragma unroll
    for (int fm = 0; fm < 4; ++fm)
#pragma unroll
      for (int fn = 0; fn < 4; ++fn)
        acc[fm][fn] = __builtin_amdgcn_mfma_f32_16x16x32_bf16(af[fm], bfr[fn], acc[fm][fn], 0, 0, 0);
  }
  float* W = ATOMIC ? W0 : (kz ? W1 : W0);
#pragma unroll
  for (int fm = 0; fm < 4; ++fm)
#pragma unroll
    for (int r = 0; r < 4; ++r) {
      const int gm = i0 + wm + fm * 16 + quad * 4 + r;
      const float sc = inv[gm];
#pragma unroll
      for (int fn = 0; fn < 4; ++fn) {
        const int gn = n0 + wn + fn * 16 + lq;
        if (ATOMIC)
          unsafeAtomicAdd(&W[(size_t)gm * DD + gn], acc[fm][fn][r] * sc);
        else
          W[(size_t)gm * DD + gn] = acc[fm][fn][r] * sc;
      }
    }
}

// ---------------- elementwise finish (FP32 out): copy / w / a-w / a*w -------
__global__ __launch_bounds__(256) void finish(const float* __restrict__ Ain,
                                              const float* __restrict__ Bin,
                                              const float* __restrict__ p1,
                                              float* __restrict__ out) {
  const int side = blockIdx.x >> 11;
  const int blk = blockIdx.x & 2047;
  const size_t idx = ((size_t)blk * 256 + threadIdx.x) * 8;
  const size_t S = (size_t)LA * DD;
  const float* src = side ? Bin : Ain;
  float* ob = out + (size_t)side * 4 * S;
  const float4 a0 = *(const float4*)&src[idx];
  const float4 a1 = *(const float4*)&src[idx + 4];
  float4 w0 = *(const float4*)&ob[S + idx];
  float4 w1 = *(const float4*)&ob[S + idx + 4];
  if (side) {
    const float4 q0 = *(const float4*)&p1[idx];
    const float4 q1 = *(const float4*)&p1[idx + 4];
    w0.x += q0.x; w0.y += q0.y; w0.z += q0.z; w0.w += q0.w;
    w1.x += q1.x; w1.y += q1.y; w1.z += q1.z; w1.w += q1.w;
    *(float4*)&ob[S + idx] = w0;
    *(float4*)&ob[S + idx + 4] = w1;
  }
  float4 s0, s1, m0, m1;
  s0.x = a0.x - w0.x; s0.y = a0.y - w0.y; s0.z = a0.z - w0.z; s0.w = a0.w - w0.w;
  s1.x = a1.x - w1.x; s1.y = a1.y - w1.y; s1.z = a1.z - w1.z; s1.w = a1.w - w1.w;
  m0.x = a0.x * w0.x; m0.y = a0.y * w0.y; m0.z = a0.z * w0.z; m0.w = a0.w * w0.w;
  m1.x = a1.x * w1.x; m1.y = a1.y * w1.y; m1.z = a1.z * w1.z; m1.w = a1.w * w1.w;
  *(float4*)&ob[idx] = a0;            *(float4*)&ob[idx + 4] = a1;
  *(float4*)&ob[2 * S + idx] = s0;    *(float4*)&ob[2 * S + idx + 4] = s1;
  *(float4*)&ob[3 * S + idx] = m0;    *(float4*)&ob[3 * S + idx + 4] = m1;
}

extern "C" void kernel_launch(void* const* d_in, const int* in_sizes, int n_in,
                              void* d_out, int out_size, void* d_ws, size_t ws_size,
                              hipStream_t stream) {
  const float* A = (const float*)d_in[0];
  const float* B = (const float*)d_in[1];
  float* out = (float*)d_out;          // FP32 output: 8 slots of S floats
  const size_t S = (size_t)LA * DD;    // 4,194,304

  // Scratch choreography inside the 128 MiB fp32 out buffer:
  //   slot0: stats (1.1MB) + Bt (u16 at float-ofs 1M); finish side0 copy LAST
  //   [S,4S): A' (24MB) + B' (24MB) during energy -> then wave_a(slot1) + P
  //   [4S,8S): E (64MB) -> then At (slot4), wave_b p0 (slot5), p1 (slot6)
  float* pmax = out;                       // 131072
  float* psum = pmax + 131072;             // 131072
  float* rmax = psum + 131072;             // unused, layout keeper
  float* rinv = rmax + 4096;
  float* cmax = rinv + 4096;
  float* cinv = cmax + 4096;
  u16*   Bt   = (u16*)(out + 1048576);     // [DD][LB] u16, 8MB
  u16*   Ap   = (u16*)(out + S);           // [4096][3072] u16, 24MB
  u16*   Bp   = Ap + (size_t)LA * 3072;    // [4096][3072] u16, 24MB
  u16*   P    = (u16*)(out + 2 * S);       // [4096][4096] u16 (after A'/B' dead)
  float* E    = out + 4 * S;               // [4096][4096] fp32, 64MB
  u16*   At   = (u16*)(out + 4 * S);       // [DD][LA] u16 (after E consumed)
  float* wave_a = out + S;
  float* wave_b = out + 5 * S;             // side-b partial 0
  float* pB1    = out + 6 * S;             // side-b partial 1

  // split A/B (concat-K) + transpose B in one launch
  prep<<<dim3(8192), 256, 0, stream>>>(A, B, Ap, Bp, Bt);

  // 8-phase energy GEMM + fused column-softmax partials
  gemm8ph<<<dim3(16, 16), 512, 0, stream>>>(Ap, Bp, E, pmax, psum);

  // row softmax + Pa in ONE E pass; also zeroes wave_a for the atomic PV
  row_softmax_pa<<<dim3(LA), 256, 0, stream>>>(E, rinv, P, wave_a);
  col_combine<<<dim3(LB / 256), 256, 0, stream>>>(pmax, psum, cmax, cinv);

  // wave_a: split-K x2 atomic into pre-zeroed slot1
  gemm_pv<1><<<dim3(DD / 128, LA / 128, 2), 256, 0, stream>>>(P, Bt, rinv, wave_a, nullptr);

  // wave_b: split-K x2, two plain partials (slot5 + slot6), summed in finish
  make_pb<<<dim3(LB / 32, LA / 32), 256, 0, stream>>>(E, cmax, P);
  tr_f32<<<dim3(DD / 32, LA / 32), 256, 0, stream>>>(A, At, LA, DD);
  gemm_pv<0><<<dim3(DD / 128, LB / 128, 2), 256, 0, stream>>>(P, At, cinv, wave_b, pB1);

  finish<<<dim3(4096), 256, 0, stream>>>(A, B, pB1, out);
}

// Round 9
// 430.756 us; speedup vs baseline: 1.2102x; 1.0214x over previous
//
#include <hip/hip_runtime.h>
#include <cstdint>
#include <cstddef>

#define LA 4096
#define LB 4096
#define DD 1024

typedef unsigned short u16;
typedef short bf16x8 __attribute__((ext_vector_type(8)));
typedef float f32x4 __attribute__((ext_vector_type(4)));

__device__ __forceinline__ u16 f2bf(float f) {
  unsigned u = __builtin_bit_cast(unsigned, f);
  u += 0x7fffu + ((u >> 16) & 1u);
  return (u16)(u >> 16);
}
__device__ __forceinline__ float bf2f(u16 h) {
  return __builtin_bit_cast(float, (unsigned)h << 16);
}
// async global->LDS, 16B/lane; lds base must be wave-uniform (HW adds lane*16)
__device__ __forceinline__ void async16(const void* g, void* l) {
  __builtin_amdgcn_global_load_lds(
      (const __attribute__((address_space(1))) unsigned int*)g,
      (__attribute__((address_space(3))) unsigned int*)l, 16, 0, 0);
}

// ---- prep: split fp32 A,B -> concat-K bf16 (A'=[hi|hi|lo], B'=[hi|lo|hi])
//      AND Bt = bf16(B^T).  blocks [0,4096): split; [4096,8192): transpose.
__global__ __launch_bounds__(256) void prep(const float* __restrict__ A,
                                            const float* __restrict__ B,
                                            u16* __restrict__ Ap,
                                            u16* __restrict__ Bp,
                                            u16* __restrict__ Bt) {
  __shared__ u16 t[32][33];
  const int bx = blockIdx.x;
  const int tid = threadIdx.x;
  if (bx < 4096) {
    const int side = bx >> 11;
    const size_t idx = ((size_t)(bx & 2047) * 256 + tid) * 8;
    const float* src = side ? B : A;
    u16* dst = side ? Bp : Ap;
    const float4 a = *(const float4*)&src[idx];
    const float4 b = *(const float4*)&src[idx + 4];
    float v[8] = {a.x, a.y, a.z, a.w, b.x, b.y, b.z, b.w};
    bf16x8 hi, lo;
#pragma unroll
    for (int i = 0; i < 8; ++i) {
      const u16 h = f2bf(v[i]);
      hi[i] = (short)h;
      lo[i] = (short)f2bf(v[i] - bf2f(h));
    }
    const size_t row = idx >> 10;
    const size_t k = idx & 1023;
    u16* base = dst + row * 3072 + k;
    *(bf16x8*)&base[0] = hi;
    *(bf16x8*)&base[side ? 2048 : 1024] = hi;
    *(bf16x8*)&base[side ? 1024 : 2048] = lo;
  } else {
    const int blk = bx - 4096;                 // tr B [LB][DD] -> Bt [DD][LB]
    const int c0 = (blk & 31) * 32;
    const int r0 = (blk >> 5) * 32;
    const int lr = tid >> 3, lc = (tid & 7) * 4;
    const float4 v = *(const float4*)&B[(size_t)(r0 + lr) * DD + c0 + lc];
    t[lr][lc + 0] = f2bf(v.x); t[lr][lc + 1] = f2bf(v.y);
    t[lr][lc + 2] = f2bf(v.z); t[lr][lc + 3] = f2bf(v.w);
    __syncthreads();
    ushort4 w;
    w.x = t[lc + 0][lr]; w.y = t[lc + 1][lr]; w.z = t[lc + 2][lr]; w.w = t[lc + 3][lr];
    *(ushort4*)&Bt[(size_t)(c0 + lr) * LB + r0 + lc] = w;
  }
}

// ------- tiled transpose fp32 -> bf16: out[c][r] = bf16(in[r][c]) -----------
__global__ __launch_bounds__(256) void tr_f32(const float* __restrict__ in,
                                              u16* __restrict__ out,
                                              int R, int C) {
  __shared__ u16 t[32][33];
  const int c0 = blockIdx.x * 32, r0 = blockIdx.y * 32;
  const int tid = threadIdx.x;
  const int lr = tid >> 3, lc = (tid & 7) * 4;
  const float4 v = *(const float4*)&in[(size_t)(r0 + lr) * C + c0 + lc];
  t[lr][lc + 0] = f2bf(v.x); t[lr][lc + 1] = f2bf(v.y);
  t[lr][lc + 2] = f2bf(v.z); t[lr][lc + 3] = f2bf(v.w);
  __syncthreads();
  ushort4 w;
  w.x = t[lc + 0][lr]; w.y = t[lc + 1][lr]; w.z = t[lc + 2][lr]; w.w = t[lc + 3][lr];
  *(ushort4*)&out[(size_t)(c0 + lr) * R + r0 + lc] = w;
}

// ======== energy: 256x256 8-phase GEMM (m201 template), K=3072 concat ======
// Same structure as R8; ONLY change: full 3-bit XOR swizzle (row&7)<<4
// (G4's conflict-free involution for 128B rows + 16B reads) replacing the
// ineffective 1-bit variant. Applied on stage-source AND ds_read (rule #21).
#define NTILES 48

#define STAGE(M, h, tt)                                                      \
  do {                                                                       \
    if ((tt) < NTILES) {                                                     \
      u16* lb = &lds[(tt) & 1][M][h][0];                                     \
      async16(gsrc[M][h][0] + (tt) * 128, lb + ldst0);                       \
      async16(gsrc[M][h][1] + (tt) * 128, lb + ldst1);                       \
    }                                                                        \
  } while (0)

#define LDA(mbase)                                                           \
  _Pragma("unroll") for (int m = 0; m < 4; ++m)                              \
  _Pragma("unroll") for (int ks = 0; ks < 2; ++ks) {                         \
    const int row = (mbase + m) * 16 + lq;                                   \
    const int cb = (ks * 64 + quad * 16) ^ ((row & 7) << 4);                 \
    af[m][ks] = *(const bf16x8*)&lds[p][0][wr][row * 64 + (cb >> 1)];        \
  }

#define LDB(arr, fbase)                                                      \
  _Pragma("unroll") for (int f = 0; f < 2; ++f)                              \
  _Pragma("unroll") for (int ks = 0; ks < 2; ++ks) {                         \
    const int row = (wc & 1) * 64 + (fbase + f) * 16 + lq;                   \
    const int cb = (ks * 64 + quad * 16) ^ ((row & 7) << 4);                 \
    arr[f][ks] = *(const bf16x8*)&lds[p][1][wc >> 1][row * 64 + (cb >> 1)];  \
  }

#define MM(mbase, fbase, barr)                                               \
  __builtin_amdgcn_s_setprio(1);                                             \
  _Pragma("unroll") for (int m = 0; m < 4; ++m)                              \
  _Pragma("unroll") for (int f = 0; f < 2; ++f)                              \
  _Pragma("unroll") for (int ks = 0; ks < 2; ++ks)                           \
    acc[mbase + m][fbase + f] = __builtin_amdgcn_mfma_f32_16x16x32_bf16(     \
        af[m][ks], barr[f][ks], acc[mbase + m][fbase + f], 0, 0, 0);         \
  __builtin_amdgcn_s_setprio(0);

#define SBAR __builtin_amdgcn_s_barrier()
#define SCHB __builtin_amdgcn_sched_barrier(0)
#define LGKM0 asm volatile("s_waitcnt lgkmcnt(0)" ::: "memory")

__global__ __launch_bounds__(512, 2) void gemm8ph(const u16* __restrict__ Ap,
                                                  const u16* __restrict__ Bp,
                                                  float* __restrict__ E,
                                                  float* __restrict__ pmax,
                                                  float* __restrict__ psum) {
  __shared__ u16 lds[2][2][2][8192];   // [buf][mat][half][128*64]
  const int tid = threadIdx.x;
  const int lane = tid & 63, quad = lane >> 4, lq = lane & 15;
  const int wave = tid >> 6;
  const int wr = wave >> 2, wc = wave & 3;
  int lin = blockIdx.y * 16 + blockIdx.x;
  lin = (lin & 7) * 32 + (lin >> 3);           // XCD-bijective (256 % 8 == 0)
  const int j0 = (lin & 15) * 256;
  const int i0 = (lin >> 4) * 256;

  // staging source precompute: linear LDS dest + inverse-swizzled global src
  const char* gsrc[2][2][2];                    // [mat][half][r]
  int ldst0, ldst1;
  {
    const int db0 = tid * 16, db1 = 8192 + tid * 16;
    const int dr0 = db0 >> 7, dr1 = db1 >> 7;
    const int sc0 = (db0 & 127) ^ ((dr0 & 7) << 4);
    const int sc1 = (db1 & 127) ^ ((dr1 & 7) << 4);
    ldst0 = wave * 512;
    ldst1 = 4096 + wave * 512;
#pragma unroll
    for (int M = 0; M < 2; ++M)
#pragma unroll
      for (int h = 0; h < 2; ++h) {
        const char* base = (const char*)(M ? Bp : Ap);
        const int rb = (M ? j0 : i0) + h * 128;
        gsrc[M][h][0] = base + (size_t)(rb + dr0) * 6144 + sc0;
        gsrc[M][h][1] = base + (size_t)(rb + dr1) * 6144 + sc1;
      }
  }

  f32x4 acc[8][4] = {};
  bf16x8 af[4][2], bf0[2][2], bf1[2][2];

  // prologue: tile0 B0,B1,A0,A1 ; vmcnt(4) ; tile1 B0,B1,A0 ; vmcnt(6)
  STAGE(1, 0, 0); STAGE(1, 1, 0); STAGE(0, 0, 0); STAGE(0, 1, 0);
  asm volatile("s_waitcnt vmcnt(4)" ::: "memory");
  STAGE(1, 0, 1); STAGE(1, 1, 1); STAGE(0, 0, 1);
  asm volatile("s_waitcnt vmcnt(6)" ::: "memory");
  SBAR;

  for (int t = 0; t < NTILES; ++t) {
    const int p = t & 1;
    // phase 0: A m0-3 + B fn0-1 ; stage (t+1).A1 ; MFMA mh0/fh0
    SCHB;
    LDA(0); LDB(bf0, 0);
    STAGE(0, 1, t + 1);
    SCHB; SBAR; LGKM0; SCHB;
    MM(0, 0, bf0);
    SCHB; SBAR;
    // phase 1: B fn2-3 ; stage (t+2).B0 ; MFMA mh0/fh1
    SCHB;
    LDB(bf1, 2);
    STAGE(1, 0, t + 2);
    SCHB; SBAR; LGKM0; SCHB;
    MM(0, 2, bf1);
    SCHB; SBAR;
    // phase 2: A m4-7 ; stage (t+2).B1 ; MFMA mh1/fh0
    SCHB;
    LDA(4);
    STAGE(1, 1, t + 2);
    SCHB; SBAR; LGKM0; SCHB;
    MM(4, 0, bf0);
    SCHB; SBAR;
    // phase 3: stage (t+2).A0 ; MFMA mh1/fh1 ; vmcnt(6)
    SCHB;
    STAGE(0, 0, t + 2);
    SCHB; SBAR; LGKM0; SCHB;
    MM(4, 2, bf1);
    SCHB;
    asm volatile("s_waitcnt vmcnt(6)" ::: "memory");
    SBAR;
  }

  // epilogue: E write + fused col-softmax partials (1 writer per cell)
  const int rbase = i0 + wr * 128;
  const int cbase = j0 + wc * 64;
#pragma unroll
  for (int fm = 0; fm < 8; ++fm)
#pragma unroll
    for (int fn = 0; fn < 4; ++fn)
#pragma unroll
      for (int r = 0; r < 4; ++r)
        E[(size_t)(rbase + fm * 16 + quad * 4 + r) * LB + cbase + fn * 16 + lq] =
            acc[fm][fn][r];
  const int rg = (i0 >> 7) + wr;               // this wave's 128-row group
#pragma unroll
  for (int fn = 0; fn < 4; ++fn) {
    float m = acc[0][fn][0];
#pragma unroll
    for (int fm = 0; fm < 8; ++fm)
#pragma unroll
      for (int r = 0; r < 4; ++r) m = fmaxf(m, acc[fm][fn][r]);
    float s = 0.f;
#pragma unroll
    for (int fm = 0; fm < 8; ++fm)
#pragma unroll
      for (int r = 0; r < 4; ++r) s += __expf(acc[fm][fn][r] - m);
#pragma unroll
    for (int mask = 16; mask <= 32; mask <<= 1) {
      const float om = __shfl_xor(m, mask);
      const float os = __shfl_xor(s, mask);
      const float nm = fmaxf(m, om);
      s = s * __expf(m - nm) + os * __expf(om - nm);
      m = nm;
    }
    if (quad == 0) {
      pmax[rg * LB + cbase + fn * 16 + lq] = m;
      psum[rg * LB + cbase + fn * 16 + lq] = s;
    }
  }
}

// ---- fused: row softmax stats + Pa[i][j]=bf16(exp(E-rmax)) + zero wave_a ---
__global__ __launch_bounds__(256) void row_softmax_pa(const float* __restrict__ E,
                                                      float* __restrict__ rinv,
                                                      u16* __restrict__ P,
                                                      float* __restrict__ wa) {
  __shared__ float red[8];
  const int row = blockIdx.x, tid = threadIdx.x;
  const float* e = E + (size_t)row * LB;
  float4 v[4];
#pragma unroll
  for (int c = 0; c < 4; ++c) v[c] = *(const float4*)&e[(c * 256 + tid) * 4];
  float m = -__builtin_inff();
#pragma unroll
  for (int c = 0; c < 4; ++c)
    m = fmaxf(m, fmaxf(fmaxf(v[c].x, v[c].y), fmaxf(v[c].z, v[c].w)));
#pragma unroll
  for (int o = 32; o > 0; o >>= 1) m = fmaxf(m, __shfl_down(m, o));
  if ((tid & 63) == 0) red[tid >> 6] = m;
  __syncthreads();
  m = fmaxf(fmaxf(red[0], red[1]), fmaxf(red[2], red[3]));
  float s = 0.f;
#pragma unroll
  for (int c = 0; c < 4; ++c)
    s += __expf(v[c].x - m) + __expf(v[c].y - m) + __expf(v[c].z - m) + __expf(v[c].w - m);
#pragma unroll
  for (int o = 32; o > 0; o >>= 1) s += __shfl_down(s, o);
  if ((tid & 63) == 0) red[4 + (tid >> 6)] = s;
  __syncthreads();
  if (tid == 0) rinv[row] = 1.f / (red[4] + red[5] + red[6] + red[7]);
#pragma unroll
  for (int c = 0; c < 4; ++c) {
    ushort4 w;
    w.x = f2bf(__expf(v[c].x - m));
    w.y = f2bf(__expf(v[c].y - m));
    w.z = f2bf(__expf(v[c].z - m));
    w.w = f2bf(__expf(v[c].w - m));
    *(ushort4*)&P[(size_t)row * LB + (c * 256 + tid) * 4] = w;
  }
  float4 z = {0.f, 0.f, 0.f, 0.f};
  *(float4*)&wa[(size_t)row * DD + tid * 4] = z;
}

// ---------------- column softmax combine ------------------------------------
__global__ __launch_bounds__(256) void col_combine(const float* __restrict__ pmax,
                                                   const float* __restrict__ psum,
                                                   float* __restrict__ cmax,
                                                   float* __restrict__ cinv) {
  const int c = blockIdx.x * 256 + threadIdx.x;
  float m = -__builtin_inff(), s = 0.f;
#pragma unroll 4
  for (int g = 0; g < 32; ++g) {
    const float pm = pmax[g * LB + c], ps = psum[g * LB + c];
    const float nm = fmaxf(m, pm);
    s = s * __expf(m - nm) + ps * __expf(pm - nm);
    m = nm;
  }
  cmax[c] = m;
  cinv[c] = 1.f / s;
}

// ---- Pb[j][i] = bf16(exp(E[i][j] - cmax[j])), transposing ------------------
__global__ __launch_bounds__(256) void make_pb(const float* __restrict__ E,
                                               const float* __restrict__ cmax,
                                               u16* __restrict__ P) {
  __shared__ u16 t[32][33];
  const int j0 = blockIdx.x * 32;
  const int i0 = blockIdx.y * 32;
  const int tid = threadIdx.x;
  const int lr = tid >> 3, lc = (tid & 7) * 4;
  const float4 v = *(const float4*)&E[(size_t)(i0 + lr) * LB + j0 + lc];
  const float4 cm = *(const float4*)&cmax[j0 + lc];
  t[lr][lc + 0] = f2bf(__expf(v.x - cm.x));
  t[lr][lc + 1] = f2bf(__expf(v.y - cm.y));
  t[lr][lc + 2] = f2bf(__expf(v.z - cm.z));
  t[lr][lc + 3] = f2bf(__expf(v.w - cm.w));
  __syncthreads();
  ushort4 w;
  w.x = t[lc + 0][lr]; w.y = t[lc + 1][lr]; w.z = t[lc + 2][lr]; w.w = t[lc + 3][lr];
  *(ushort4*)&P[(size_t)(j0 + lr) * LA + i0 + lc] = w;
}

// ---- W[i][d] = inv[i] * sum_j P[i][j] Vt[d][j], split-K x2 -----------------
template <int ATOMIC>
__global__ __launch_bounds__(256) void gemm_pv(const u16* __restrict__ P,
                                               const u16* __restrict__ Vt,
                                               const float* __restrict__ inv,
                                               float* __restrict__ W0,
                                               float* __restrict__ W1) {
  __shared__ u16 lds_a[128 * 32];
  __shared__ u16 lds_b[128 * 32];
  const int n0 = blockIdx.x * 128;
  const int i0 = blockIdx.y * 128;
  const int kz = blockIdx.z;
  const int tid = threadIdx.x;
  const int lane = tid & 63, quad = lane >> 4, lq = lane & 15;
  const int wave = tid >> 6;
  const int wm = (wave & 1) * 64, wn = (wave >> 1) * 64;
  f32x4 acc[4][4] = {};
  for (int t = 0; t < 64; ++t) {
    const int kt = kz * 2048 + t * 32;
    if (t) __syncthreads();
#pragma unroll
    for (int r = 0; r < 2; ++r) {
      const int chunk = wave * 128 + r * 64 + lane;
      const int row = chunk >> 2;
      const int kc = (chunk & 3) * 8;
      const int lofs = (wave * 128 + r * 64) * 16;
      async16(P + (size_t)(i0 + row) * 4096 + kt + kc, (char*)lds_a + lofs);
      async16(Vt + (size_t)(n0 + row) * 4096 + kt + kc, (char*)lds_b + lofs);
    }
    __syncthreads();
    bf16x8 af[4], bfr[4];
#pragma unroll
    for (int f = 0; f < 4; ++f) {
      af[f]  = *(const bf16x8*)&lds_a[(wm + f * 16 + lq) * 32 + quad * 8];
      bfr[f] = *(const bf16x8*)&lds_b[(wn + f * 16 + lq) * 32 + quad * 8];
    }
#pragma unroll
    for (int fm = 0; fm < 4; ++fm)
#pragma unroll
      for (int fn = 0; fn < 4; ++fn)
        acc[fm][fn] = __builtin_amdgcn_mfma_f32_16x16x32_bf16(af[fm], bfr[fn], acc[fm][fn], 0, 0, 0);
  }
  float* W = ATOMIC ? W0 : (kz ? W1 : W0);
#pragma unroll
  for (int fm = 0; fm < 4; ++fm)
#pragma unroll
    for (int r = 0; r < 4; ++r) {
      const int gm = i0 + wm + fm * 16 + quad * 4 + r;
      const float sc = inv[gm];
#pragma unroll
      for (int fn = 0; fn < 4; ++fn) {
        const int gn = n0 + wn + fn * 16 + lq;
        if (ATOMIC)
          unsafeAtomicAdd(&W[(size_t)gm * DD + gn], acc[fm][fn][r] * sc);
        else
          W[(size_t)gm * DD + gn] = acc[fm][fn][r] * sc;
      }
    }
}

// ---------------- elementwise finish (FP32 out): copy / w / a-w / a*w -------
__global__ __launch_bounds__(256) void finish(const float* __restrict__ Ain,
                                              const float* __restrict__ Bin,
                                              const float* __restrict__ p1,
                                              float* __restrict__ out) {
  const int side = blockIdx.x >> 11;
  const int blk = blockIdx.x & 2047;
  const size_t idx = ((size_t)blk * 256 + threadIdx.x) * 8;
  const size_t S = (size_t)LA * DD;
  const float* src = side ? Bin : Ain;
  float* ob = out + (size_t)side * 4 * S;
  const float4 a0 = *(const float4*)&src[idx];
  const float4 a1 = *(const float4*)&src[idx + 4];
  float4 w0 = *(const float4*)&ob[S + idx];
  float4 w1 = *(const float4*)&ob[S + idx + 4];
  if (side) {
    const float4 q0 = *(const float4*)&p1[idx];
    const float4 q1 = *(const float4*)&p1[idx + 4];
    w0.x += q0.x; w0.y += q0.y; w0.z += q0.z; w0.w += q0.w;
    w1.x += q1.x; w1.y += q1.y; w1.z += q1.z; w1.w += q1.w;
    *(float4*)&ob[S + idx] = w0;
    *(float4*)&ob[S + idx + 4] = w1;
  }
  float4 s0, s1, m0, m1;
  s0.x = a0.x - w0.x; s0.y = a0.y - w0.y; s0.z = a0.z - w0.z; s0.w = a0.w - w0.w;
  s1.x = a1.x - w1.x; s1.y = a1.y - w1.y; s1.z = a1.z - w1.z; s1.w = a1.w - w1.w;
  m0.x = a0.x * w0.x; m0.y = a0.y * w0.y; m0.z = a0.z * w0.z; m0.w = a0.w * w0.w;
  m1.x = a1.x * w1.x; m1.y = a1.y * w1.y; m1.z = a1.z * w1.z; m1.w = a1.w * w1.w;
  *(float4*)&ob[idx] = a0;            *(float4*)&ob[idx + 4] = a1;
  *(float4*)&ob[2 * S + idx] = s0;    *(float4*)&ob[2 * S + idx + 4] = s1;
  *(float4*)&ob[3 * S + idx] = m0;    *(float4*)&ob[3 * S + idx + 4] = m1;
}

extern "C" void kernel_launch(void* const* d_in, const int* in_sizes, int n_in,
                              void* d_out, int out_size, void* d_ws, size_t ws_size,
                              hipStream_t stream) {
  const float* A = (const float*)d_in[0];
  const float* B = (const float*)d_in[1];
  float* out = (float*)d_out;          // FP32 output: 8 slots of S floats
  const size_t S = (size_t)LA * DD;    // 4,194,304

  // Scratch choreography inside the 128 MiB fp32 out buffer:
  //   slot0: stats (1.1MB) + Bt (u16 at float-ofs 1M); finish side0 copy LAST
  //   [S,4S): A' (24MB) + B' (24MB) during energy -> then wave_a(slot1) + P
  //   [4S,8S): E (64MB) -> then At (slot4), wave_b p0 (slot5), p1 (slot6)
  float* pmax = out;                       // 131072
  float* psum = pmax + 131072;             // 131072
  float* rmax = psum + 131072;             // unused, layout keeper
  float* rinv = rmax + 4096;
  float* cmax = rinv + 4096;
  float* cinv = cmax + 4096;
  u16*   Bt   = (u16*)(out + 1048576);     // [DD][LB] u16, 8MB
  u16*   Ap   = (u16*)(out + S);           // [4096][3072] u16, 24MB
  u16*   Bp   = Ap + (size_t)LA * 3072;    // [4096][3072] u16, 24MB
  u16*   P    = (u16*)(out + 2 * S);       // [4096][4096] u16 (after A'/B' dead)
  float* E    = out + 4 * S;               // [4096][4096] fp32, 64MB
  u16*   At   = (u16*)(out + 4 * S);       // [DD][LA] u16 (after E consumed)
  float* wave_a = out + S;
  float* wave_b = out + 5 * S;             // side-b partial 0
  float* pB1    = out + 6 * S;             // side-b partial 1

  // split A/B (concat-K) + transpose B in one launch
  prep<<<dim3(8192), 256, 0, stream>>>(A, B, Ap, Bp, Bt);

  // 8-phase energy GEMM + fused column-softmax partials
  gemm8ph<<<dim3(16, 16), 512, 0, stream>>>(Ap, Bp, E, pmax, psum);

  // row softmax + Pa in ONE E pass; also zeroes wave_a for the atomic PV
  row_softmax_pa<<<dim3(LA), 256, 0, stream>>>(E, rinv, P, wave_a);
  col_combine<<<dim3(LB / 256), 256, 0, stream>>>(pmax, psum, cmax, cinv);

  // wave_a: split-K x2 atomic into pre-zeroed slot1
  gemm_pv<1><<<dim3(DD / 128, LA / 128, 2), 256, 0, stream>>>(P, Bt, rinv, wave_a, nullptr);

  // wave_b: split-K x2, two plain partials (slot5 + slot6), summed in finish
  make_pb<<<dim3(LB / 32, LA / 32), 256, 0, stream>>>(E, cmax, P);
  tr_f32<<<dim3(DD / 32, LA / 32), 256, 0, stream>>>(A, At, LA, DD);
  gemm_pv<0><<<dim3(DD / 128, LB / 128, 2), 256, 0, stream>>>(P, At, cinv, wave_b, pB1);

  finish<<<dim3(4096), 256, 0, stream>>>(A, B, pB1, out);
}

// Round 10
// 415.209 us; speedup vs baseline: 1.2555x; 1.0374x over previous
//
#include <hip/hip_runtime.h>
#include <cstdint>
#include <cstddef>

#define LA 4096
#define LB 4096
#define DD 1024

typedef unsigned short u16;
typedef short bf16x8 __attribute__((ext_vector_type(8)));
typedef float f32x4 __attribute__((ext_vector_type(4)));

__device__ __forceinline__ u16 f2bf(float f) {
  unsigned u = __builtin_bit_cast(unsigned, f);
  u += 0x7fffu + ((u >> 16) & 1u);
  return (u16)(u >> 16);
}
__device__ __forceinline__ float bf2f(u16 h) {
  return __builtin_bit_cast(float, (unsigned)h << 16);
}
// async global->LDS, 16B/lane; lds base must be wave-uniform (HW adds lane*16)
__device__ __forceinline__ void async16(const void* g, void* l) {
  __builtin_amdgcn_global_load_lds(
      (const __attribute__((address_space(1))) unsigned int*)g,
      (__attribute__((address_space(3))) unsigned int*)l, 16, 0, 0);
}

// ---- prep: split fp32 A,B -> concat-K bf16 (A'=[hi|hi|lo], B'=[hi|lo|hi])
//      AND Bt = bf16(B^T).  blocks [0,4096): split; [4096,8192): transpose.
__global__ __launch_bounds__(256) void prep(const float* __restrict__ A,
                                            const float* __restrict__ B,
                                            u16* __restrict__ Ap,
                                            u16* __restrict__ Bp,
                                            u16* __restrict__ Bt) {
  __shared__ u16 t[32][33];
  const int bx = blockIdx.x;
  const int tid = threadIdx.x;
  if (bx < 4096) {
    const int side = bx >> 11;
    const size_t idx = ((size_t)(bx & 2047) * 256 + tid) * 8;
    const float* src = side ? B : A;
    u16* dst = side ? Bp : Ap;
    const float4 a = *(const float4*)&src[idx];
    const float4 b = *(const float4*)&src[idx + 4];
    float v[8] = {a.x, a.y, a.z, a.w, b.x, b.y, b.z, b.w};
    bf16x8 hi, lo;
#pragma unroll
    for (int i = 0; i < 8; ++i) {
      const u16 h = f2bf(v[i]);
      hi[i] = (short)h;
      lo[i] = (short)f2bf(v[i] - bf2f(h));
    }
    const size_t row = idx >> 10;
    const size_t k = idx & 1023;
    u16* base = dst + row * 3072 + k;
    *(bf16x8*)&base[0] = hi;
    *(bf16x8*)&base[side ? 2048 : 1024] = hi;
    *(bf16x8*)&base[side ? 1024 : 2048] = lo;
  } else {
    const int blk = bx - 4096;                 // tr B [LB][DD] -> Bt [DD][LB]
    const int c0 = (blk & 31) * 32;
    const int r0 = (blk >> 5) * 32;
    const int lr = tid >> 3, lc = (tid & 7) * 4;
    const float4 v = *(const float4*)&B[(size_t)(r0 + lr) * DD + c0 + lc];
    t[lr][lc + 0] = f2bf(v.x); t[lr][lc + 1] = f2bf(v.y);
    t[lr][lc + 2] = f2bf(v.z); t[lr][lc + 3] = f2bf(v.w);
    __syncthreads();
    ushort4 w;
    w.x = t[lc + 0][lr]; w.y = t[lc + 1][lr]; w.z = t[lc + 2][lr]; w.w = t[lc + 3][lr];
    *(ushort4*)&Bt[(size_t)(c0 + lr) * LB + r0 + lc] = w;
  }
}

// ------- tiled transpose fp32 -> bf16: out[c][r] = bf16(in[r][c]) -----------
__global__ __launch_bounds__(256) void tr_f32(const float* __restrict__ in,
                                              u16* __restrict__ out,
                                              int R, int C) {
  __shared__ u16 t[32][33];
  const int c0 = blockIdx.x * 32, r0 = blockIdx.y * 32;
  const int tid = threadIdx.x;
  const int lr = tid >> 3, lc = (tid & 7) * 4;
  const float4 v = *(const float4*)&in[(size_t)(r0 + lr) * C + c0 + lc];
  t[lr][lc + 0] = f2bf(v.x); t[lr][lc + 1] = f2bf(v.y);
  t[lr][lc + 2] = f2bf(v.z); t[lr][lc + 3] = f2bf(v.w);
  __syncthreads();
  ushort4 w;
  w.x = t[lc + 0][lr]; w.y = t[lc + 1][lr]; w.z = t[lc + 2][lr]; w.w = t[lc + 3][lr];
  *(ushort4*)&out[(size_t)(c0 + lr) * R + r0 + lc] = w;
}

// ======== energy: 256x256 8-phase GEMM (m201 template), K=3072 concat ======
// Frozen from R9 (103 us, bank-conflict 0, MfmaUtil 41%).
#define NTILES 48

#define STAGE(M, h, tt)                                                      \
  do {                                                                       \
    if ((tt) < NTILES) {                                                     \
      u16* lb = &lds[(tt) & 1][M][h][0];                                     \
      async16(gsrc[M][h][0] + (tt) * 128, lb + ldst0);                       \
      async16(gsrc[M][h][1] + (tt) * 128, lb + ldst1);                       \
    }                                                                        \
  } while (0)

#define LDA(mbase)                                                           \
  _Pragma("unroll") for (int m = 0; m < 4; ++m)                              \
  _Pragma("unroll") for (int ks = 0; ks < 2; ++ks) {                         \
    const int row = (mbase + m) * 16 + lq;                                   \
    const int cb = (ks * 64 + quad * 16) ^ ((row & 7) << 4);                 \
    af[m][ks] = *(const bf16x8*)&lds[p][0][wr][row * 64 + (cb >> 1)];        \
  }

#define LDB(arr, fbase)                                                      \
  _Pragma("unroll") for (int f = 0; f < 2; ++f)                              \
  _Pragma("unroll") for (int ks = 0; ks < 2; ++ks) {                         \
    const int row = (wc & 1) * 64 + (fbase + f) * 16 + lq;                   \
    const int cb = (ks * 64 + quad * 16) ^ ((row & 7) << 4);                 \
    arr[f][ks] = *(const bf16x8*)&lds[p][1][wc >> 1][row * 64 + (cb >> 1)];  \
  }

#define MM(mbase, fbase, barr)                                               \
  __builtin_amdgcn_s_setprio(1);                                             \
  _Pragma("unroll") for (int m = 0; m < 4; ++m)                              \
  _Pragma("unroll") for (int f = 0; f < 2; ++f)                              \
  _Pragma("unroll") for (int ks = 0; ks < 2; ++ks)                           \
    acc[mbase + m][fbase + f] = __builtin_amdgcn_mfma_f32_16x16x32_bf16(     \
        af[m][ks], barr[f][ks], acc[mbase + m][fbase + f], 0, 0, 0);         \
  __builtin_amdgcn_s_setprio(0);

#define SBAR __builtin_amdgcn_s_barrier()
#define SCHB __builtin_amdgcn_sched_barrier(0)
#define LGKM0 asm volatile("s_waitcnt lgkmcnt(0)" ::: "memory")

__global__ __launch_bounds__(512, 2) void gemm8ph(const u16* __restrict__ Ap,
                                                  const u16* __restrict__ Bp,
                                                  float* __restrict__ E,
                                                  float* __restrict__ pmax,
                                                  float* __restrict__ psum) {
  __shared__ u16 lds[2][2][2][8192];   // [buf][mat][half][128*64]
  const int tid = threadIdx.x;
  const int lane = tid & 63, quad = lane >> 4, lq = lane & 15;
  const int wave = tid >> 6;
  const int wr = wave >> 2, wc = wave & 3;
  int lin = blockIdx.y * 16 + blockIdx.x;
  lin = (lin & 7) * 32 + (lin >> 3);           // XCD-bijective (256 % 8 == 0)
  const int j0 = (lin & 15) * 256;
  const int i0 = (lin >> 4) * 256;

  // staging source precompute: linear LDS dest + inverse-swizzled global src
  const char* gsrc[2][2][2];                    // [mat][half][r]
  int ldst0, ldst1;
  {
    const int db0 = tid * 16, db1 = 8192 + tid * 16;
    const int dr0 = db0 >> 7, dr1 = db1 >> 7;
    const int sc0 = (db0 & 127) ^ ((dr0 & 7) << 4);
    const int sc1 = (db1 & 127) ^ ((dr1 & 7) << 4);
    ldst0 = wave * 512;
    ldst1 = 4096 + wave * 512;
#pragma unroll
    for (int M = 0; M < 2; ++M)
#pragma unroll
      for (int h = 0; h < 2; ++h) {
        const char* base = (const char*)(M ? Bp : Ap);
        const int rb = (M ? j0 : i0) + h * 128;
        gsrc[M][h][0] = base + (size_t)(rb + dr0) * 6144 + sc0;
        gsrc[M][h][1] = base + (size_t)(rb + dr1) * 6144 + sc1;
      }
  }

  f32x4 acc[8][4] = {};
  bf16x8 af[4][2], bf0[2][2], bf1[2][2];

  // prologue: tile0 B0,B1,A0,A1 ; vmcnt(4) ; tile1 B0,B1,A0 ; vmcnt(6)
  STAGE(1, 0, 0); STAGE(1, 1, 0); STAGE(0, 0, 0); STAGE(0, 1, 0);
  asm volatile("s_waitcnt vmcnt(4)" ::: "memory");
  STAGE(1, 0, 1); STAGE(1, 1, 1); STAGE(0, 0, 1);
  asm volatile("s_waitcnt vmcnt(6)" ::: "memory");
  SBAR;

  for (int t = 0; t < NTILES; ++t) {
    const int p = t & 1;
    // phase 0: A m0-3 + B fn0-1 ; stage (t+1).A1 ; MFMA mh0/fh0
    SCHB;
    LDA(0); LDB(bf0, 0);
    STAGE(0, 1, t + 1);
    SCHB; SBAR; LGKM0; SCHB;
    MM(0, 0, bf0);
    SCHB; SBAR;
    // phase 1: B fn2-3 ; stage (t+2).B0 ; MFMA mh0/fh1
    SCHB;
    LDB(bf1, 2);
    STAGE(1, 0, t + 2);
    SCHB; SBAR; LGKM0; SCHB;
    MM(0, 2, bf1);
    SCHB; SBAR;
    // phase 2: A m4-7 ; stage (t+2).B1 ; MFMA mh1/fh0
    SCHB;
    LDA(4);
    STAGE(1, 1, t + 2);
    SCHB; SBAR; LGKM0; SCHB;
    MM(4, 0, bf0);
    SCHB; SBAR;
    // phase 3: stage (t+2).A0 ; MFMA mh1/fh1 ; vmcnt(6)
    SCHB;
    STAGE(0, 0, t + 2);
    SCHB; SBAR; LGKM0; SCHB;
    MM(4, 2, bf1);
    SCHB;
    asm volatile("s_waitcnt vmcnt(6)" ::: "memory");
    SBAR;
  }

  // epilogue: E write + fused col-softmax partials (1 writer per cell)
  const int rbase = i0 + wr * 128;
  const int cbase = j0 + wc * 64;
#pragma unroll
  for (int fm = 0; fm < 8; ++fm)
#pragma unroll
    for (int fn = 0; fn < 4; ++fn)
#pragma unroll
      for (int r = 0; r < 4; ++r)
        E[(size_t)(rbase + fm * 16 + quad * 4 + r) * LB + cbase + fn * 16 + lq] =
            acc[fm][fn][r];
  const int rg = (i0 >> 7) + wr;               // this wave's 128-row group
#pragma unroll
  for (int fn = 0; fn < 4; ++fn) {
    float m = acc[0][fn][0];
#pragma unroll
    for (int fm = 0; fm < 8; ++fm)
#pragma unroll
      for (int r = 0; r < 4; ++r) m = fmaxf(m, acc[fm][fn][r]);
    float s = 0.f;
#pragma unroll
    for (int fm = 0; fm < 8; ++fm)
#pragma unroll
      for (int r = 0; r < 4; ++r) s += __expf(acc[fm][fn][r] - m);
#pragma unroll
    for (int mask = 16; mask <= 32; mask <<= 1) {
      const float om = __shfl_xor(m, mask);
      const float os = __shfl_xor(s, mask);
      const float nm = fmaxf(m, om);
      s = s * __expf(m - nm) + os * __expf(om - nm);
      m = nm;
    }
    if (quad == 0) {
      pmax[rg * LB + cbase + fn * 16 + lq] = m;
      psum[rg * LB + cbase + fn * 16 + lq] = s;
    }
  }
}

// ---- fused: row softmax stats + Pa[i][j]=bf16(exp(E-rmax)) + zero wave_a ---
__global__ __launch_bounds__(256) void row_softmax_pa(const float* __restrict__ E,
                                                      float* __restrict__ rinv,
                                                      u16* __restrict__ P,
                                                      float* __restrict__ wa) {
  __shared__ float red[8];
  const int row = blockIdx.x, tid = threadIdx.x;
  const float* e = E + (size_t)row * LB;
  float4 v[4];
#pragma unroll
  for (int c = 0; c < 4; ++c) v[c] = *(const float4*)&e[(c * 256 + tid) * 4];
  float m = -__builtin_inff();
#pragma unroll
  for (int c = 0; c < 4; ++c)
    m = fmaxf(m, fmaxf(fmaxf(v[c].x, v[c].y), fmaxf(v[c].z, v[c].w)));
#pragma unroll
  for (int o = 32; o > 0; o >>= 1) m = fmaxf(m, __shfl_down(m, o));
  if ((tid & 63) == 0) red[tid >> 6] = m;
  __syncthreads();
  m = fmaxf(fmaxf(red[0], red[1]), fmaxf(red[2], red[3]));
  float s = 0.f;
#pragma unroll
  for (int c = 0; c < 4; ++c)
    s += __expf(v[c].x - m) + __expf(v[c].y - m) + __expf(v[c].z - m) + __expf(v[c].w - m);
#pragma unroll
  for (int o = 32; o > 0; o >>= 1) s += __shfl_down(s, o);
  if ((tid & 63) == 0) red[4 + (tid >> 6)] = s;
  __syncthreads();
  if (tid == 0) rinv[row] = 1.f / (red[4] + red[5] + red[6] + red[7]);
#pragma unroll
  for (int c = 0; c < 4; ++c) {
    ushort4 w;
    w.x = f2bf(__expf(v[c].x - m));
    w.y = f2bf(__expf(v[c].y - m));
    w.z = f2bf(__expf(v[c].z - m));
    w.w = f2bf(__expf(v[c].w - m));
    *(ushort4*)&P[(size_t)row * LB + (c * 256 + tid) * 4] = w;
  }
  float4 z = {0.f, 0.f, 0.f, 0.f};
  *(float4*)&wa[(size_t)row * DD + tid * 4] = z;
}

// ---------------- column softmax combine ------------------------------------
__global__ __launch_bounds__(256) void col_combine(const float* __restrict__ pmax,
                                                   const float* __restrict__ psum,
                                                   float* __restrict__ cmax,
                                                   float* __restrict__ cinv) {
  const int c = blockIdx.x * 256 + threadIdx.x;
  float m = -__builtin_inff(), s = 0.f;
#pragma unroll 4
  for (int g = 0; g < 32; ++g) {
    const float pm = pmax[g * LB + c], ps = psum[g * LB + c];
    const float nm = fmaxf(m, pm);
    s = s * __expf(m - nm) + ps * __expf(pm - nm);
    m = nm;
  }
  cmax[c] = m;
  cinv[c] = 1.f / s;
}

// ---- Pb[j][i] = bf16(exp(E[i][j] - cmax[j])), transposing ------------------
__global__ __launch_bounds__(256) void make_pb(const float* __restrict__ E,
                                               const float* __restrict__ cmax,
                                               u16* __restrict__ P) {
  __shared__ u16 t[32][33];
  const int j0 = blockIdx.x * 32;
  const int i0 = blockIdx.y * 32;
  const int tid = threadIdx.x;
  const int lr = tid >> 3, lc = (tid & 7) * 4;
  const float4 v = *(const float4*)&E[(size_t)(i0 + lr) * LB + j0 + lc];
  const float4 cm = *(const float4*)&cmax[j0 + lc];
  t[lr][lc + 0] = f2bf(__expf(v.x - cm.x));
  t[lr][lc + 1] = f2bf(__expf(v.y - cm.y));
  t[lr][lc + 2] = f2bf(__expf(v.z - cm.z));
  t[lr][lc + 3] = f2bf(__expf(v.w - cm.w));
  __syncthreads();
  ushort4 w;
  w.x = t[lc + 0][lr]; w.y = t[lc + 1][lr]; w.z = t[lc + 2][lr]; w.w = t[lc + 3][lr];
  *(ushort4*)&P[(size_t)(j0 + lr) * LA + i0 + lc] = w;
}

// ---- W[i][d] = inv[i] * sum_j P[i][j] Vt[d][j], split-K x2 -----------------
// BK=64 (32KB staged / 32 MFMA per barrier-step, halving barrier count) +
// (row&7) 16B-slot XOR swizzle: pre-swizzled per-lane global source, same
// XOR on ds_read -> 2-way (free) instead of 8-way LDS conflicts.
// Accumulation k-order identical to BK=32 version (bit-identical results).
// ATOMIC=1: both K-halves unsafeAtomicAdd into pre-zeroed W0.
// ATOMIC=0: kz=0 -> W0, kz=1 -> W1 plain stores; consumer sums partials.
template <int ATOMIC>
__global__ __launch_bounds__(256) void gemm_pv(const u16* __restrict__ P,
                                               const u16* __restrict__ Vt,
                                               const float* __restrict__ inv,
                                               float* __restrict__ W0,
                                               float* __restrict__ W1) {
  __shared__ u16 lds_a[128 * 64];
  __shared__ u16 lds_b[128 * 64];
  const int n0 = blockIdx.x * 128;
  const int i0 = blockIdx.y * 128;
  const int kz = blockIdx.z;
  const int tid = threadIdx.x;
  const int lane = tid & 63, quad = lane >> 4, lq = lane & 15;
  const int wave = tid >> 6;
  const int wm = (wave & 1) * 64, wn = (wave >> 1) * 64;

  // staging precompute: 4 chunks/thread x 16B; dest linear (wave-uniform
  // base + lane*16), source slot inverse-swizzled within each 128B row.
  size_t poff[4], voff[4];
  int lofs[4];
#pragma unroll
  for (int r = 0; r < 4; ++r) {
    const int c = r * 256 + wave * 64 + lane;    // chunk 0..1023
    const int row = c >> 3;                       // 0..127
    const int slot = (c & 7) ^ (row & 7);         // swizzled source slot
    lofs[r] = (r * 256 + wave * 64) * 16;         // wave-uniform dest (bytes)
    poff[r] = (size_t)(i0 + row) * 4096 + slot * 8;
    voff[r] = (size_t)(n0 + row) * 4096 + slot * 8;
  }

  f32x4 acc[4][4] = {};
  for (int t = 0; t < 32; ++t) {
    const int kt = kz * 2048 + t * 64;
    if (t) __syncthreads();
#pragma unroll
    for (int r = 0; r < 4; ++r) {
      async16(P + poff[r] + kt, (char*)lds_a + lofs[r]);
      async16(Vt + voff[r] + kt, (char*)lds_b + lofs[r]);
    }
    __syncthreads();
    bf16x8 af[4][2], bfr[4][2];
#pragma unroll
    for (int f = 0; f < 4; ++f)
#pragma unroll
      for (int ks = 0; ks < 2; ++ks) {
        const int ra = wm + f * 16 + lq;
        const int rb = wn + f * 16 + lq;
        const int ca = ((ks * 64 + quad * 16) ^ ((ra & 7) << 4)) >> 1;
        const int cb = ((ks * 64 + quad * 16) ^ ((rb & 7) << 4)) >> 1;
        af[f][ks]  = *(const bf16x8*)&lds_a[ra * 64 + ca];
        bfr[f][ks] = *(const bf16x8*)&lds_b[rb * 64 + cb];
      }
#pragma unroll
    for (int fm = 0; fm < 4; ++fm)
#pragma unroll
      for (int fn = 0; fn < 4; ++fn)
#pragma unroll
        for (int ks = 0; ks < 2; ++ks)
          acc[fm][fn] = __builtin_amdgcn_mfma_f32_16x16x32_bf16(
              af[fm][ks], bfr[fn][ks], acc[fm][fn], 0, 0, 0);
  }
  float* W = ATOMIC ? W0 : (kz ? W1 : W0);
#pragma unroll
  for (int fm = 0; fm < 4; ++fm)
#pragma unroll
    for (int r = 0; r < 4; ++r) {
      const int gm = i0 + wm + fm * 16 + quad * 4 + r;
      const float sc = inv[gm];
#pragma unroll
      for (int fn = 0; fn < 4; ++fn) {
        const int gn = n0 + wn + fn * 16 + lq;
        if (ATOMIC)
          unsafeAtomicAdd(&W[(size_t)gm * DD + gn], acc[fm][fn][r] * sc);
        else
          W[(size_t)gm * DD + gn] = acc[fm][fn][r] * sc;
      }
    }
}

// ---------------- elementwise finish (FP32 out): copy / w / a-w / a*w -------
__global__ __launch_bounds__(256) void finish(const float* __restrict__ Ain,
                                              const float* __restrict__ Bin,
                                              const float* __restrict__ p1,
                                              float* __restrict__ out) {
  const int side = blockIdx.x >> 11;
  const int blk = blockIdx.x & 2047;
  const size_t idx = ((size_t)blk * 256 + threadIdx.x) * 8;
  const size_t S = (size_t)LA * DD;
  const float* src = side ? Bin : Ain;
  float* ob = out + (size_t)side * 4 * S;
  const float4 a0 = *(const float4*)&src[idx];
  const float4 a1 = *(const float4*)&src[idx + 4];
  float4 w0 = *(const float4*)&ob[S + idx];
  float4 w1 = *(const float4*)&ob[S + idx + 4];
  if (side) {
    const float4 q0 = *(const float4*)&p1[idx];
    const float4 q1 = *(const float4*)&p1[idx + 4];
    w0.x += q0.x; w0.y += q0.y; w0.z += q0.z; w0.w += q0.w;
    w1.x += q1.x; w1.y += q1.y; w1.z += q1.z; w1.w += q1.w;
    *(float4*)&ob[S + idx] = w0;
    *(float4*)&ob[S + idx + 4] = w1;
  }
  float4 s0, s1, m0, m1;
  s0.x = a0.x - w0.x; s0.y = a0.y - w0.y; s0.z = a0.z - w0.z; s0.w = a0.w - w0.w;
  s1.x = a1.x - w1.x; s1.y = a1.y - w1.y; s1.z = a1.z - w1.z; s1.w = a1.w - w1.w;
  m0.x = a0.x * w0.x; m0.y = a0.y * w0.y; m0.z = a0.z * w0.z; m0.w = a0.w * w0.w;
  m1.x = a1.x * w1.x; m1.y = a1.y * w1.y; m1.z = a1.z * w1.z; m1.w = a1.w * w1.w;
  *(float4*)&ob[idx] = a0;            *(float4*)&ob[idx + 4] = a1;
  *(float4*)&ob[2 * S + idx] = s0;    *(float4*)&ob[2 * S + idx + 4] = s1;
  *(float4*)&ob[3 * S + idx] = m0;    *(float4*)&ob[3 * S + idx + 4] = m1;
}

extern "C" void kernel_launch(void* const* d_in, const int* in_sizes, int n_in,
                              void* d_out, int out_size, void* d_ws, size_t ws_size,
                              hipStream_t stream) {
  const float* A = (const float*)d_in[0];
  const float* B = (const float*)d_in[1];
  float* out = (float*)d_out;          // FP32 output: 8 slots of S floats
  const size_t S = (size_t)LA * DD;    // 4,194,304

  // Scratch choreography inside the 128 MiB fp32 out buffer:
  //   slot0: stats (1.1MB) + Bt (u16 at float-ofs 1M); finish side0 copy LAST
  //   [S,4S): A' (24MB) + B' (24MB) during energy -> then wave_a(slot1) + P
  //   [4S,8S): E (64MB) -> then At (slot4), wave_b p0 (slot5), p1 (slot6)
  float* pmax = out;                       // 131072
  float* psum = pmax + 131072;             // 131072
  float* rmax = psum + 131072;             // unused, layout keeper
  float* rinv = rmax + 4096;
  float* cmax = rinv + 4096;
  float* cinv = cmax + 4096;
  u16*   Bt   = (u16*)(out + 1048576);     // [DD][LB] u16, 8MB
  u16*   Ap   = (u16*)(out + S);           // [4096][3072] u16, 24MB
  u16*   Bp   = Ap + (size_t)LA * 3072;    // [4096][3072] u16, 24MB
  u16*   P    = (u16*)(out + 2 * S);       // [4096][4096] u16 (after A'/B' dead)
  float* E    = out + 4 * S;               // [4096][4096] fp32, 64MB
  u16*   At   = (u16*)(out + 4 * S);       // [DD][LA] u16 (after E consumed)
  float* wave_a = out + S;
  float* wave_b = out + 5 * S;             // side-b partial 0
  float* pB1    = out + 6 * S;             // side-b partial 1

  // split A/B (concat-K) + transpose B in one launch
  prep<<<dim3(8192), 256, 0, stream>>>(A, B, Ap, Bp, Bt);

  // 8-phase energy GEMM + fused column-softmax partials
  gemm8ph<<<dim3(16, 16), 512, 0, stream>>>(Ap, Bp, E, pmax, psum);

  // row softmax + Pa in ONE E pass; also zeroes wave_a for the atomic PV
  row_softmax_pa<<<dim3(LA), 256, 0, stream>>>(E, rinv, P, wave_a);
  col_combine<<<dim3(LB / 256), 256, 0, stream>>>(pmax, psum, cmax, cinv);

  // wave_a: split-K x2 atomic into pre-zeroed slot1
  gemm_pv<1><<<dim3(DD / 128, LA / 128, 2), 256, 0, stream>>>(P, Bt, rinv, wave_a, nullptr);

  // wave_b: split-K x2, two plain partials (slot5 + slot6), summed in finish
  make_pb<<<dim3(LB / 32, LA / 32), 256, 0, stream>>>(E, cmax, P);
  tr_f32<<<dim3(DD / 32, LA / 32), 256, 0, stream>>>(A, At, LA, DD);
  gemm_pv<0><<<dim3(DD / 128, LB / 128, 2), 256, 0, stream>>>(P, At, cinv, wave_b, pB1);

  finish<<<dim3(4096), 256, 0, stream>>>(A, B, pB1, out);
}